// Round 8
// baseline (451.240 us; speedup 1.0000x reference)
//
#include <hip/hip_runtime.h>
#include <math.h>

typedef __bf16 bf16;
typedef __bf16 bf16x4 __attribute__((ext_vector_type(4)));
typedef __bf16 bf16x8 __attribute__((ext_vector_type(8)));
typedef float f32x4 __attribute__((ext_vector_type(4)));

__device__ __forceinline__ f32x4 mfma16(bf16x8 a, bf16x8 b, f32x4 c) {
  return __builtin_amdgcn_mfma_f32_16x16x32_bf16(a, b, c, 0, 0, 0);
}

__device__ __forceinline__ void gload_lds16(const void* g, void* l) {
  __builtin_amdgcn_global_load_lds((__attribute__((address_space(1))) void*)(g),
                                   (__attribute__((address_space(3))) void*)(l),
                                   16, 0, 0);
}

// ---------------- fused weight conversion + bias concat (1 launch) ----------
__global__ __launch_bounds__(256)
void cvt_all(const float* __restrict__ Wq, const float* __restrict__ Wk,
             const float* __restrict__ Wv, const float* __restrict__ Wo,
             const float* __restrict__ W1, const float* __restrict__ W2,
             const float* __restrict__ bq, const float* __restrict__ bk,
             const float* __restrict__ bv, bf16* __restrict__ wqkv,
             bf16* __restrict__ wob, bf16* __restrict__ w1b,
             bf16* __restrict__ w2b, float* __restrict__ bqkv) {
  const int i = blockIdx.x * 256 + threadIdx.x;
  if (i < 3145728) {
    float4 v;
    bf16* dst;
    size_t di;
    if (i < 262144) { v = ((const float4*)Wq)[i]; dst = wqkv; di = i; }
    else if (i < 524288) { v = ((const float4*)Wk)[i - 262144]; dst = wqkv; di = i; }
    else if (i < 786432) { v = ((const float4*)Wv)[i - 524288]; dst = wqkv; di = i; }
    else if (i < 1048576) { v = ((const float4*)Wo)[i - 786432]; dst = wob; di = i - 786432; }
    else if (i < 2097152) { v = ((const float4*)W1)[i - 1048576]; dst = w1b; di = i - 1048576; }
    else { v = ((const float4*)W2)[i - 2097152]; dst = w2b; di = i - 2097152; }
    bf16x4 o;
    o[0] = (bf16)v.x; o[1] = (bf16)v.y; o[2] = (bf16)v.z; o[3] = (bf16)v.w;
    reinterpret_cast<bf16x4*>(dst)[di] = o;
  } else {
    const int j = i - 3145728;  // 0..767
    const float* s = (j < 256) ? bq : ((j < 512) ? bk : bv);
    reinterpret_cast<float4*>(bqkv)[j] = reinterpret_cast<const float4*>(s)[j & 255];
  }
}

// ---------------- LayerNorm fp32 -> bf16, D=1024, block=256 ----------------
__global__ __launch_bounds__(256)
void ln_bf16(const float* __restrict__ x, const float* __restrict__ g,
             const float* __restrict__ bta, bf16* __restrict__ y) {
  const int row = blockIdx.x, t = threadIdx.x;
  const float4 v = reinterpret_cast<const float4*>(x)[(size_t)row * 256 + t];
  float s1 = v.x + v.y + v.z + v.w;
  float s2 = v.x * v.x + v.y * v.y + v.z * v.z + v.w * v.w;
#pragma unroll
  for (int m = 1; m < 64; m <<= 1) {
    s1 += __shfl_xor(s1, m);
    s2 += __shfl_xor(s2, m);
  }
  __shared__ float red[8];
  if ((t & 63) == 0) { red[(t >> 6) * 2] = s1; red[(t >> 6) * 2 + 1] = s2; }
  __syncthreads();
  s1 = red[0] + red[2] + red[4] + red[6];
  s2 = red[1] + red[3] + red[5] + red[7];
  const float mu = s1 * (1.f / 1024.f);
  const float rs = rsqrtf(s2 * (1.f / 1024.f) - mu * mu + 1e-5f);
  const float4 gv = reinterpret_cast<const float4*>(g)[t];
  const float4 bv = reinterpret_cast<const float4*>(bta)[t];
  bf16x4 o;
  o[0] = (bf16)((v.x - mu) * rs * gv.x + bv.x);
  o[1] = (bf16)((v.y - mu) * rs * gv.y + bv.y);
  o[2] = (bf16)((v.z - mu) * rs * gv.z + bv.z);
  o[3] = (bf16)((v.w - mu) * rs * gv.w + bv.w);
  reinterpret_cast<bf16x4*>(y)[(size_t)row * 256 + t] = o;
}

// ---------------- V transpose: QKV V-part -> VT[b,h,d,s] ----------------
__global__ __launch_bounds__(256)
void tr_v(const bf16* __restrict__ QKV, bf16* __restrict__ VT) {
  __shared__ bf16 T[64 * 80];
  const int t = threadIdx.x;
  const int sb = blockIdx.x * 64, h = blockIdx.y, b = blockIdx.z;
  const int srow = t >> 2, c16 = t & 3;
  const bf16* src = QKV + (size_t)(b * 2048 + sb + srow) * 3072 + 2048 + h * 64 + c16 * 16;
  bf16x8 a0 = *reinterpret_cast<const bf16x8*>(src);
  bf16x8 a1 = *reinterpret_cast<const bf16x8*>(src + 8);
  *reinterpret_cast<bf16x8*>(&T[srow * 80 + c16 * 16]) = a0;
  *reinterpret_cast<bf16x8*>(&T[srow * 80 + c16 * 16 + 8]) = a1;
  __syncthreads();
  const int drow = t >> 2, sq = t & 3;
  bf16x8 o0, o1;
#pragma unroll
  for (int j = 0; j < 8; ++j) o0[j] = T[(sq * 16 + j) * 80 + drow];
#pragma unroll
  for (int j = 0; j < 8; ++j) o1[j] = T[(sq * 16 + 8 + j) * 80 + drow];
  bf16* dst = VT + ((size_t)(b * 16 + h) * 64 + drow) * 2048 + sb + sq * 16;
  *reinterpret_cast<bf16x8*>(dst) = o0;
  *reinterpret_cast<bf16x8*>(dst + 8) = o1;
}

// ---------------- GEMM: C[M,N] = act(A[M,K] @ Bw[N,K]^T + bias) (+res) --------
// 128x128 tile, BK=32, 4 waves, 16x16x32 MFMA, glds w16, XCD swizzle,
// 2-phase double-buffered staging (T3-minimum).
template <bool OUT_BF16, bool RELU, bool RES, bool QSC>
__global__ __launch_bounds__(256)
void gemm_bt(const bf16* __restrict__ A, const bf16* __restrict__ Bw,
             const float* __restrict__ bias, const float* __restrict__ res,
             void* __restrict__ Cout, int M, int N, int K) {
  __shared__ bf16 As[2][128 * 32];
  __shared__ bf16 Bs[2][128 * 32];
  const int t = threadIdx.x, wave = t >> 6, lane = t & 63;
  const int l15 = lane & 15, lhi = lane >> 4;
  const int nwg = gridDim.x * gridDim.y;
  const int orig = blockIdx.y * gridDim.x + blockIdx.x;
  const int wgid = (orig & 7) * (nwg >> 3) + (orig >> 3);
  const int bx = wgid % gridDim.x, by = wgid / gridDim.x;
  const int m0 = by * 128, n0 = bx * 128;
  const int wm = (wave >> 1) * 64, wn = (wave & 1) * 64;
  const f32x4 z4 = {0.f, 0.f, 0.f, 0.f};
  f32x4 acc[4][4];
#pragma unroll
  for (int m = 0; m < 4; ++m)
#pragma unroll
    for (int n = 0; n < 4; ++n) acc[m][n] = z4;

  const int soff0 = wave * 1024 + lane * 16;
  const int soff1 = (4 + wave) * 1024 + lane * 16;
  const int srow0 = soff0 >> 6, scol0 = (soff0 & 63) >> 1;
  const int srow1 = soff1 >> 6, scol1 = (soff1 & 63) >> 1;

#define GEMM_STAGE(k0, bb)                                                    \
  do {                                                                        \
    gload_lds16(A + (size_t)(m0 + srow0) * K + (k0) + scol0,                  \
                (char*)As[bb] + soff0);                                       \
    gload_lds16(Bw + (size_t)(n0 + srow0) * K + (k0) + scol0,                 \
                (char*)Bs[bb] + soff0);                                       \
    gload_lds16(A + (size_t)(m0 + srow1) * K + (k0) + scol1,                  \
                (char*)As[bb] + soff1);                                       \
    gload_lds16(Bw + (size_t)(n0 + srow1) * K + (k0) + scol1,                 \
                (char*)Bs[bb] + soff1);                                       \
  } while (0)

  GEMM_STAGE(0, 0);
  asm volatile("s_waitcnt vmcnt(0)" ::: "memory");
  __builtin_amdgcn_s_barrier();

  int cur = 0;
  for (int k0 = 0; k0 < K; k0 += 32) {
    if (k0 + 32 < K) GEMM_STAGE(k0 + 32, cur ^ 1);
    bf16x8 af[4], bfr[4];
#pragma unroll
    for (int m = 0; m < 4; ++m)
      af[m] = *reinterpret_cast<const bf16x8*>(&As[cur][(wm + m * 16 + l15) * 32 + lhi * 8]);
#pragma unroll
    for (int n = 0; n < 4; ++n)
      bfr[n] = *reinterpret_cast<const bf16x8*>(&Bs[cur][(wn + n * 16 + l15) * 32 + lhi * 8]);
    __builtin_amdgcn_s_setprio(1);
#pragma unroll
    for (int m = 0; m < 4; ++m)
#pragma unroll
      for (int n = 0; n < 4; ++n) acc[m][n] = mfma16(af[m], bfr[n], acc[m][n]);
    __builtin_amdgcn_s_setprio(0);
    asm volatile("s_waitcnt vmcnt(0)" ::: "memory");
    __builtin_amdgcn_s_barrier();
    cur ^= 1;
  }
#undef GEMM_STAGE

  const float sc = (QSC && n0 < 1024) ? 0.125f : 1.0f;
#pragma unroll
  for (int m = 0; m < 4; ++m) {
    const int row_base = m0 + wm + m * 16 + lhi * 4;
#pragma unroll
    for (int n = 0; n < 4; ++n) {
      const int col = n0 + wn + n * 16 + l15;
      const float bv = bias[col];
#pragma unroll
      for (int r = 0; r < 4; ++r) {
        const int row = row_base + r;
        float v = (acc[m][n][r] + bv) * sc;
        if (RELU) v = v > 0.f ? v : 0.f;
        if (RES) v += res[(size_t)row * N + col];
        if (OUT_BF16)
          ((bf16*)Cout)[(size_t)row * N + col] = (bf16)v;
        else
          ((float*)Cout)[(size_t)row * N + col] = v;
      }
    }
  }
}

// ---------------- Fused attention v2.2: QBLK=128, 8 waves, T14 + T5 ---------
// grid 512 blocks (XCD-swizzled), 8 waves, 128 q rows/block (16/wave).
// Swapped QK^T: mfma(K, Q) -> lane holds q-row = l15, kv = n*16+lhi*4+r.
// No max subtraction (scores bounded; constant shift 15; mask -> exact 0).
// T14: tile t+1 global loads issued into regs BEFORE compute of tile t;
// ds_write (swizzled) after the read-done barrier.
__global__ __launch_bounds__(512)
void attn_fused2(const bf16* __restrict__ Qp, const bf16* __restrict__ Kp,
                 const bf16* __restrict__ VTp, const int* __restrict__ mask,
                 float* __restrict__ probs, bf16* __restrict__ Ob) {
  constexpr int S = 2048, LD = 3072, KB = 128, NT = S / KB;
  __shared__ bf16 Kt[KB * 64];    // [128 kv][64 d], rows 128B, swizzled (16KB)
  __shared__ bf16 Vt[64 * KB];    // [64 d][128 kv], rows 256B, swizzled (16KB)
  __shared__ bf16 P[128 * KB];    // [128 q][128 kv], rows 256B, swizzled (32KB)
  __shared__ float msk[KB];
  const int t = threadIdx.x, wave = t >> 6, lane = t & 63;
  const int l15 = lane & 15, lhi = lane >> 4;
  const int flat = blockIdx.x + 16 * (blockIdx.y + 16 * blockIdx.z);
  const int wg = (flat & 7) * 64 + (flat >> 3);
  const int q0 = (wg & 15) * 128, h = (wg >> 4) & 15, b = wg >> 8;
  const int* mrow = mask + b * S;
  const f32x4 z4 = {0.f, 0.f, 0.f, 0.f};

  // per-thread staging map: 2 chunks of 16B each for K and for V (512 thr)
  const bf16* kgp[2];
  const bf16* vgp[2];
  int soff[2];
#pragma unroll
  for (int i = 0; i < 2; ++i) {
    const int off = (i * 8 + wave) * 1024 + lane * 16;
    soff[i] = off;
    const int krow = off >> 7, kbin = off & 127;
    kgp[i] = Kp + (size_t)(b * S + krow) * LD + h * 64 + ((kbin ^ ((krow & 7) << 4)) >> 1);
    const int d = off >> 8, vbin = off & 255;
    vgp[i] = VTp + (size_t)((b * 16 + h) * 64 + d) * S + ((vbin ^ ((d & 7) << 4)) >> 1);
  }

  bf16x8 qf[2];
#pragma unroll
  for (int ks = 0; ks < 2; ++ks)
    qf[ks] = *reinterpret_cast<const bf16x8*>(
        Qp + (size_t)(b * S + q0 + wave * 16 + l15) * LD + h * 64 + ks * 32 + lhi * 8);

  // ================= pass A: l = sum over kv of exp(s - 15) =================
  bf16x8 kreg[2];
  float mnext;
#pragma unroll
  for (int i = 0; i < 2; ++i) kreg[i] = *reinterpret_cast<const bf16x8*>(kgp[i]);
  mnext = (t < KB) ? (mrow[t] ? 0.f : 1.f) : 0.f;
#pragma unroll
  for (int i = 0; i < 2; ++i)
    *reinterpret_cast<bf16x8*>((char*)Kt + soff[i]) = kreg[i];
  if (t < KB) msk[t] = mnext;
  __syncthreads();

  float lpart = 0.f;
  for (int kt = 0; kt < NT; ++kt) {
    const int kv0 = kt * KB;
    if (kt + 1 < NT) {  // issue-early: next K tile -> regs
#pragma unroll
      for (int i = 0; i < 2; ++i)
        kreg[i] = *reinterpret_cast<const bf16x8*>(kgp[i] + (size_t)(kv0 + KB) * LD);
      mnext = (t < KB) ? (mrow[kv0 + KB + t] ? 0.f : 1.f) : 0.f;
    }
    f32x4 sa[8];
#pragma unroll
    for (int n = 0; n < 8; ++n) sa[n] = z4;
    __builtin_amdgcn_s_setprio(1);
#pragma unroll
    for (int ks = 0; ks < 2; ++ks)
#pragma unroll
      for (int n = 0; n < 8; ++n) {
        const int krow = n * 16 + l15;
        bf16x8 kf = *reinterpret_cast<const bf16x8*>(
            (char*)Kt + krow * 128 + ((ks * 64 + lhi * 16) ^ ((krow & 7) << 4)));
        sa[n] = mfma16(kf, qf[ks], sa[n]);
      }
    __builtin_amdgcn_s_setprio(0);
#pragma unroll
    for (int n = 0; n < 8; ++n)
#pragma unroll
      for (int r = 0; r < 4; ++r)
        lpart += __expf(sa[n][r] - 15.f) * msk[n * 16 + lhi * 4 + r];
    __syncthreads();  // Kt reads done
    if (kt + 1 < NT) {  // write-late
#pragma unroll
      for (int i = 0; i < 2; ++i)
        *reinterpret_cast<bf16x8*>((char*)Kt + soff[i]) = kreg[i];
      if (t < KB) msk[t] = mnext;
    }
    __syncthreads();  // staging visible
  }
  lpart += __shfl_xor(lpart, 16);
  lpart += __shfl_xor(lpart, 32);
  const float il = 1.f / lpart;  // for q-row = wave*16 + l15

  // ================= pass B: probs + PV =================
  f32x4 oa[4];
#pragma unroll
  for (int n = 0; n < 4; ++n) oa[n] = z4;
  float* pbase = probs + ((size_t)(b * 16 + h) * S + q0 + wave * 16 + l15) * S;
  const int prw = wave * 16 + l15;

  bf16x8 vreg[2];
#pragma unroll
  for (int i = 0; i < 2; ++i) {
    kreg[i] = *reinterpret_cast<const bf16x8*>(kgp[i]);
    vreg[i] = *reinterpret_cast<const bf16x8*>(vgp[i]);
  }
  mnext = (t < KB) ? (mrow[t] ? 0.f : 1.f) : 0.f;
  // prev pass's last barrier guarantees no wave is still reading Kt
#pragma unroll
  for (int i = 0; i < 2; ++i) {
    *reinterpret_cast<bf16x8*>((char*)Kt + soff[i]) = kreg[i];
    *reinterpret_cast<bf16x8*>((char*)Vt + soff[i]) = vreg[i];
  }
  if (t < KB) msk[t] = mnext;
  __syncthreads();

  for (int kt = 0; kt < NT; ++kt) {
    const int kv0 = kt * KB;
    if (kt + 1 < NT) {  // issue-early: next K+V tiles -> regs
#pragma unroll
      for (int i = 0; i < 2; ++i) {
        kreg[i] = *reinterpret_cast<const bf16x8*>(kgp[i] + (size_t)(kv0 + KB) * LD);
        vreg[i] = *reinterpret_cast<const bf16x8*>(vgp[i] + kv0 + KB);
      }
      mnext = (t < KB) ? (mrow[kv0 + KB + t] ? 0.f : 1.f) : 0.f;
    }

    f32x4 sa[8];
#pragma unroll
    for (int n = 0; n < 8; ++n) sa[n] = z4;
    __builtin_amdgcn_s_setprio(1);
#pragma unroll
    for (int ks = 0; ks < 2; ++ks)
#pragma unroll
      for (int n = 0; n < 8; ++n) {
        const int krow = n * 16 + l15;
        bf16x8 kf = *reinterpret_cast<const bf16x8*>(
            (char*)Kt + krow * 128 + ((ks * 64 + lhi * 16) ^ ((krow & 7) << 4)));
        sa[n] = mfma16(kf, qf[ks], sa[n]);
      }
    __builtin_amdgcn_s_setprio(0);

#pragma unroll
    for (int n = 0; n < 8; ++n) {
      f32x4 pn;
#pragma unroll
      for (int r = 0; r < 4; ++r)
        pn[r] = __expf(sa[n][r] - 15.f) * msk[n * 16 + lhi * 4 + r] * il;
      *reinterpret_cast<f32x4*>(pbase + kv0 + n * 16 + lhi * 4) = pn;
      bf16x4 pb;
      pb[0] = (bf16)pn[0]; pb[1] = (bf16)pn[1];
      pb[2] = (bf16)pn[2]; pb[3] = (bf16)pn[3];
      *reinterpret_cast<bf16x4*>(
          (char*)P + prw * 256 + ((n * 32 + lhi * 8) ^ ((prw & 7) << 4))) = pb;
    }
    __builtin_amdgcn_s_setprio(1);
#pragma unroll
    for (int ks = 0; ks < 4; ++ks) {
      bf16x8 pf = *reinterpret_cast<const bf16x8*>(
          (char*)P + prw * 256 + ((ks * 64 + lhi * 16) ^ ((prw & 7) << 4)));
#pragma unroll
      for (int nn = 0; nn < 4; ++nn) {
        const int vr = nn * 16 + l15;
        bf16x8 vf = *reinterpret_cast<const bf16x8*>(
            (char*)Vt + vr * 256 + ((ks * 64 + lhi * 16) ^ ((vr & 7) << 4)));
        oa[nn] = mfma16(pf, vf, oa[nn]);
      }
    }
    __builtin_amdgcn_s_setprio(0);
    __syncthreads();  // Kt/Vt reads done
    if (kt + 1 < NT) {  // write-late
#pragma unroll
      for (int i = 0; i < 2; ++i) {
        *reinterpret_cast<bf16x8*>((char*)Kt + soff[i]) = kreg[i];
        *reinterpret_cast<bf16x8*>((char*)Vt + soff[i]) = vreg[i];
      }
      if (t < KB) msk[t] = mnext;
    }
    __syncthreads();  // staging visible
  }

#pragma unroll
  for (int nn = 0; nn < 4; ++nn)
#pragma unroll
    for (int r = 0; r < 4; ++r)
      Ob[(size_t)(b * S + q0 + wave * 16 + lhi * 4 + r) * 1024 + h * 64 + nn * 16 + l15] =
          (bf16)oa[nn][r];
}

// ---------------- launch ----------------
extern "C" void kernel_launch(void* const* d_in, const int* in_sizes, int n_in,
                              void* d_out, int out_size, void* d_ws, size_t ws_size,
                              hipStream_t stream) {
  const float* src = (const float*)d_in[0];
  const int* mask = (const int*)d_in[1];
  const float* Wq = (const float*)d_in[2];
  const float* bq = (const float*)d_in[3];
  const float* Wk = (const float*)d_in[4];
  const float* bk = (const float*)d_in[5];
  const float* Wv = (const float*)d_in[6];
  const float* bv = (const float*)d_in[7];
  const float* Wo = (const float*)d_in[8];
  const float* bo = (const float*)d_in[9];
  const float* W1 = (const float*)d_in[10];
  const float* b1 = (const float*)d_in[11];
  const float* W2 = (const float*)d_in[12];
  const float* b2 = (const float*)d_in[13];
  const float* ln1g = (const float*)d_in[14];
  const float* ln1b = (const float*)d_in[15];
  const float* ln2g = (const float*)d_in[16];
  const float* ln2b = (const float*)d_in[17];

  float* out0 = (float*)d_out;                       // [2,2048,1024]
  float* probs = (float*)d_out + (size_t)4194304;    // [2,16,2048,2048]

  char* w = (char*)d_ws;
  const size_t MB = 1u << 20;
  bf16* wqkv = (bf16*)(w);              // [3072,1024] rows: Wq|Wk|Wv (6MB)
  bf16* wob = (bf16*)(w + 6 * MB);      // [1024,1024]
  bf16* w1b = (bf16*)(w + 8 * MB);      // [4096,1024]
  bf16* w2b = (bf16*)(w + 16 * MB);     // [1024,4096]
  bf16* xn = (bf16*)(w + 24 * MB);      // [4096,1024]
  bf16* QKV = (bf16*)(w + 32 * MB);     // [4096,3072] (24MB)
  bf16* Ob = (bf16*)(w + 56 * MB);      // [4096,1024]
  bf16* hb = (bf16*)(w + 32 * MB);      // [4096,4096] reuse (QKV dead by then)
  bf16* VT = (bf16*)(w + 64 * MB);      // [2,16,64,2048] (8MB); dead after attn
  float* s2 = (float*)(w + 64 * MB);    // [4096,1024] fp32 (16MB) overlays VT
  float* bqkv = (float*)(w + 80 * MB);  // [3072]

  // fused weight conversion + bias concat (1 launch)
  cvt_all<<<12291, 256, 0, stream>>>(Wq, Wk, Wv, Wo, W1, W2, bq, bk, bv,
                                     wqkv, wob, w1b, w2b, bqkv);

  // LN1
  ln_bf16<<<4096, 256, 0, stream>>>(src, ln1g, ln1b, xn);
  // fused QKV projection (Q part pre-scaled by 1/8)
  gemm_bt<true, false, false, true><<<dim3(24, 32), 256, 0, stream>>>(
      xn, wqkv, bqkv, nullptr, QKV, 4096, 3072, 1024);
  // V transpose for attn staging
  tr_v<<<dim3(32, 16, 2), 256, 0, stream>>>(QKV, VT);
  // fused attention (QBLK=128, 8 waves)
  attn_fused2<<<dim3(16, 16, 2), 512, 0, stream>>>(
      QKV, QKV + 1024, VT, mask, probs, Ob);
  // Wo + residual(src) -> s2 (fp32)
  gemm_bt<false, false, true, false><<<dim3(8, 32), 256, 0, stream>>>(
      Ob, wob, bo, src, s2, 4096, 1024, 1024);
  // LN2
  ln_bf16<<<4096, 256, 0, stream>>>(s2, ln2g, ln2b, xn);
  // FFN1 + ReLU
  gemm_bt<true, true, false, false><<<dim3(32, 32), 256, 0, stream>>>(
      xn, w1b, b1, nullptr, hb, 4096, 4096, 1024);
  // FFN2 + residual(s2) -> out0
  gemm_bt<false, false, true, false><<<dim3(8, 32), 256, 0, stream>>>(
      hb, w2b, b2, s2, out0, 4096, 1024, 4096);

  (void)in_sizes; (void)n_in; (void)out_size; (void)ws_size;
}

// Round 9
// 434.813 us; speedup vs baseline: 1.0378x; 1.0378x over previous
//
#include <hip/hip_runtime.h>
#include <math.h>

typedef __bf16 bf16;
typedef __bf16 bf16x4 __attribute__((ext_vector_type(4)));
typedef __bf16 bf16x8 __attribute__((ext_vector_type(8)));
typedef float f32x4 __attribute__((ext_vector_type(4)));

__device__ __forceinline__ f32x4 mfma16(bf16x8 a, bf16x8 b, f32x4 c) {
  return __builtin_amdgcn_mfma_f32_16x16x32_bf16(a, b, c, 0, 0, 0);
}

__device__ __forceinline__ void gload_lds16(const void* g, void* l) {
  __builtin_amdgcn_global_load_lds((__attribute__((address_space(1))) void*)(g),
                                   (__attribute__((address_space(3))) void*)(l),
                                   16, 0, 0);
}

// ---------------- fused weight conversion + bias concat (1 launch) ----------
__global__ __launch_bounds__(256)
void cvt_all(const float* __restrict__ Wq, const float* __restrict__ Wk,
             const float* __restrict__ Wv, const float* __restrict__ Wo,
             const float* __restrict__ W1, const float* __restrict__ W2,
             const float* __restrict__ bq, const float* __restrict__ bk,
             const float* __restrict__ bv, bf16* __restrict__ wqkv,
             bf16* __restrict__ wob, bf16* __restrict__ w1b,
             bf16* __restrict__ w2b, float* __restrict__ bqkv) {
  const int i = blockIdx.x * 256 + threadIdx.x;
  if (i < 3145728) {
    float4 v;
    bf16* dst;
    size_t di;
    if (i < 262144) { v = ((const float4*)Wq)[i]; dst = wqkv; di = i; }
    else if (i < 524288) { v = ((const float4*)Wk)[i - 262144]; dst = wqkv; di = i; }
    else if (i < 786432) { v = ((const float4*)Wv)[i - 524288]; dst = wqkv; di = i; }
    else if (i < 1048576) { v = ((const float4*)Wo)[i - 786432]; dst = wob; di = i - 786432; }
    else if (i < 2097152) { v = ((const float4*)W1)[i - 1048576]; dst = w1b; di = i - 1048576; }
    else { v = ((const float4*)W2)[i - 2097152]; dst = w2b; di = i - 2097152; }
    bf16x4 o;
    o[0] = (bf16)v.x; o[1] = (bf16)v.y; o[2] = (bf16)v.z; o[3] = (bf16)v.w;
    reinterpret_cast<bf16x4*>(dst)[di] = o;
  } else {
    const int j = i - 3145728;  // 0..767
    const float* s = (j < 256) ? bq : ((j < 512) ? bk : bv);
    reinterpret_cast<float4*>(bqkv)[j] = reinterpret_cast<const float4*>(s)[j & 255];
  }
}

// ---------------- LayerNorm fp32 -> bf16, D=1024, block=256 ----------------
__global__ __launch_bounds__(256)
void ln_bf16(const float* __restrict__ x, const float* __restrict__ g,
             const float* __restrict__ bta, bf16* __restrict__ y) {
  const int row = blockIdx.x, t = threadIdx.x;
  const float4 v = reinterpret_cast<const float4*>(x)[(size_t)row * 256 + t];
  float s1 = v.x + v.y + v.z + v.w;
  float s2 = v.x * v.x + v.y * v.y + v.z * v.z + v.w * v.w;
#pragma unroll
  for (int m = 1; m < 64; m <<= 1) {
    s1 += __shfl_xor(s1, m);
    s2 += __shfl_xor(s2, m);
  }
  __shared__ float red[8];
  if ((t & 63) == 0) { red[(t >> 6) * 2] = s1; red[(t >> 6) * 2 + 1] = s2; }
  __syncthreads();
  s1 = red[0] + red[2] + red[4] + red[6];
  s2 = red[1] + red[3] + red[5] + red[7];
  const float mu = s1 * (1.f / 1024.f);
  const float rs = rsqrtf(s2 * (1.f / 1024.f) - mu * mu + 1e-5f);
  const float4 gv = reinterpret_cast<const float4*>(g)[t];
  const float4 bv = reinterpret_cast<const float4*>(bta)[t];
  bf16x4 o;
  o[0] = (bf16)((v.x - mu) * rs * gv.x + bv.x);
  o[1] = (bf16)((v.y - mu) * rs * gv.y + bv.y);
  o[2] = (bf16)((v.z - mu) * rs * gv.z + bv.z);
  o[3] = (bf16)((v.w - mu) * rs * gv.w + bv.w);
  reinterpret_cast<bf16x4*>(y)[(size_t)row * 256 + t] = o;
}

// ---------------- V transpose: QKV V-part -> VT[b,h,d,s] ----------------
__global__ __launch_bounds__(256)
void tr_v(const bf16* __restrict__ QKV, bf16* __restrict__ VT) {
  __shared__ bf16 T[64 * 80];
  const int t = threadIdx.x;
  const int sb = blockIdx.x * 64, h = blockIdx.y, b = blockIdx.z;
  const int srow = t >> 2, c16 = t & 3;
  const bf16* src = QKV + (size_t)(b * 2048 + sb + srow) * 3072 + 2048 + h * 64 + c16 * 16;
  bf16x8 a0 = *reinterpret_cast<const bf16x8*>(src);
  bf16x8 a1 = *reinterpret_cast<const bf16x8*>(src + 8);
  *reinterpret_cast<bf16x8*>(&T[srow * 80 + c16 * 16]) = a0;
  *reinterpret_cast<bf16x8*>(&T[srow * 80 + c16 * 16 + 8]) = a1;
  __syncthreads();
  const int drow = t >> 2, sq = t & 3;
  bf16x8 o0, o1;
#pragma unroll
  for (int j = 0; j < 8; ++j) o0[j] = T[(sq * 16 + j) * 80 + drow];
#pragma unroll
  for (int j = 0; j < 8; ++j) o1[j] = T[(sq * 16 + 8 + j) * 80 + drow];
  bf16* dst = VT + ((size_t)(b * 16 + h) * 64 + drow) * 2048 + sb + sq * 16;
  *reinterpret_cast<bf16x8*>(dst) = o0;
  *reinterpret_cast<bf16x8*>(dst + 8) = o1;
}

// ---------------- GEMM: C[M,N] = act(A[M,K] @ Bw[N,K]^T + bias) (+res) --------
// 128x128 tile, BK=32, 4 waves, 16x16x32 MFMA, glds w16, XCD swizzle.
// Counted-vmcnt depth-2 pipeline (T4): 3 LDS buffers, prefetch 2 tiles ahead,
// s_waitcnt vmcnt(4) per tile (tile t+2's 4 loads stay in flight across the
// barrier; only t+1's must land).
template <bool OUT_BF16, bool RELU, bool RES, bool QSC>
__global__ __launch_bounds__(256)
void gemm_bt(const bf16* __restrict__ A, const bf16* __restrict__ Bw,
             const float* __restrict__ bias, const float* __restrict__ res,
             void* __restrict__ Cout, int M, int N, int K) {
  __shared__ bf16 As[3][128 * 32];
  __shared__ bf16 Bs[3][128 * 32];
  const int t = threadIdx.x, wave = t >> 6, lane = t & 63;
  const int l15 = lane & 15, lhi = lane >> 4;
  const int nwg = gridDim.x * gridDim.y;
  const int orig = blockIdx.y * gridDim.x + blockIdx.x;
  const int wgid = (orig & 7) * (nwg >> 3) + (orig >> 3);
  const int bx = wgid % gridDim.x, by = wgid / gridDim.x;
  const int m0 = by * 128, n0 = bx * 128;
  const int wm = (wave >> 1) * 64, wn = (wave & 1) * 64;
  const f32x4 z4 = {0.f, 0.f, 0.f, 0.f};
  f32x4 acc[4][4];
#pragma unroll
  for (int m = 0; m < 4; ++m)
#pragma unroll
    for (int n = 0; n < 4; ++n) acc[m][n] = z4;

  const int soff0 = wave * 1024 + lane * 16;
  const int soff1 = (4 + wave) * 1024 + lane * 16;
  const int srow0 = soff0 >> 6, scol0 = (soff0 & 63) >> 1;
  const int srow1 = soff1 >> 6, scol1 = (soff1 & 63) >> 1;

#define GEMM_STAGE(k0, bb)                                                    \
  do {                                                                        \
    gload_lds16(A + (size_t)(m0 + srow0) * K + (k0) + scol0,                  \
                (char*)As[bb] + soff0);                                       \
    gload_lds16(Bw + (size_t)(n0 + srow0) * K + (k0) + scol0,                 \
                (char*)Bs[bb] + soff0);                                       \
    gload_lds16(A + (size_t)(m0 + srow1) * K + (k0) + scol1,                  \
                (char*)As[bb] + soff1);                                       \
    gload_lds16(Bw + (size_t)(n0 + srow1) * K + (k0) + scol1,                 \
                (char*)Bs[bb] + soff1);                                       \
  } while (0)

  const int nt = K >> 5;
  GEMM_STAGE(0, 0);
  GEMM_STAGE(32, 1);
  asm volatile("s_waitcnt vmcnt(4)" ::: "memory");  // tile 0 landed
  __builtin_amdgcn_s_barrier();

  for (int kt = 0; kt < nt; ++kt) {
    if (kt + 2 < nt) GEMM_STAGE((kt + 2) * 32, (kt + 2) % 3);
    const bf16* Ac = As[kt % 3];
    const bf16* Bc = Bs[kt % 3];
    bf16x8 af[4], bfr[4];
#pragma unroll
    for (int m = 0; m < 4; ++m)
      af[m] = *reinterpret_cast<const bf16x8*>(&Ac[(wm + m * 16 + l15) * 32 + lhi * 8]);
#pragma unroll
    for (int n = 0; n < 4; ++n)
      bfr[n] = *reinterpret_cast<const bf16x8*>(&Bc[(wn + n * 16 + l15) * 32 + lhi * 8]);
    __builtin_amdgcn_s_setprio(1);
#pragma unroll
    for (int m = 0; m < 4; ++m)
#pragma unroll
      for (int n = 0; n < 4; ++n) acc[m][n] = mfma16(af[m], bfr[n], acc[m][n]);
    __builtin_amdgcn_s_setprio(0);
    if (kt + 1 < nt) {
      if (kt + 2 < nt)
        asm volatile("s_waitcnt vmcnt(4)" ::: "memory");  // t+1 landed, t+2 in flight
      else
        asm volatile("s_waitcnt vmcnt(0)" ::: "memory");  // last prefetch drained
      __builtin_amdgcn_s_barrier();
    }
  }
#undef GEMM_STAGE

  const float sc = (QSC && n0 < 1024) ? 0.125f : 1.0f;
#pragma unroll
  for (int m = 0; m < 4; ++m) {
    const int row_base = m0 + wm + m * 16 + lhi * 4;
#pragma unroll
    for (int n = 0; n < 4; ++n) {
      const int col = n0 + wn + n * 16 + l15;
      const float bv = bias[col];
#pragma unroll
      for (int r = 0; r < 4; ++r) {
        const int row = row_base + r;
        float v = (acc[m][n][r] + bv) * sc;
        if (RELU) v = v > 0.f ? v : 0.f;
        if (RES) v += res[(size_t)row * N + col];
        if (OUT_BF16)
          ((bf16*)Cout)[(size_t)row * N + col] = (bf16)v;
        else
          ((float*)Cout)[(size_t)row * N + col] = v;
      }
    }
  }
}

// ---------------- Fused attention: QBLK=128, 8 waves, T14 ----------------
// grid 512 blocks (XCD-swizzled), 8 waves, 128 q rows/block (16/wave).
// Swapped QK^T: mfma(K, Q) -> lane holds q-row = l15, kv = n*16+lhi*4+r.
// No max subtraction (scores bounded; constant shift 15; mask -> exact 0).
// Pass A: K tile ping-pongs between Kt and Vt regions (Vt idle in pass A) +
// double-buffered msk -> 1 barrier/tile. Pass B: 2 barriers/tile (T14).
__global__ __launch_bounds__(512)
void attn_fused2(const bf16* __restrict__ Qp, const bf16* __restrict__ Kp,
                 const bf16* __restrict__ VTp, const int* __restrict__ mask,
                 float* __restrict__ probs, bf16* __restrict__ Ob) {
  constexpr int S = 2048, LD = 3072, KB = 128, NT = S / KB;
  __shared__ bf16 Kt[KB * 64];    // [128 kv][64 d], rows 128B, swizzled (16KB)
  __shared__ bf16 Vt[64 * KB];    // pass A: K ping buffer; pass B: [64 d][128 kv]
  __shared__ bf16 P[128 * KB];    // [128 q][128 kv], rows 256B, swizzled (32KB)
  __shared__ float msk2[2][KB];
  const int t = threadIdx.x, wave = t >> 6, lane = t & 63;
  const int l15 = lane & 15, lhi = lane >> 4;
  const int flat = blockIdx.x + 16 * (blockIdx.y + 16 * blockIdx.z);
  const int wg = (flat & 7) * 64 + (flat >> 3);
  const int q0 = (wg & 15) * 128, h = (wg >> 4) & 15, b = wg >> 8;
  const int* mrow = mask + b * S;
  const f32x4 z4 = {0.f, 0.f, 0.f, 0.f};

  // per-thread staging map: 2 chunks of 16B each for K and for V (512 thr)
  const bf16* kgp[2];
  const bf16* vgp[2];
  int soff[2];
#pragma unroll
  for (int i = 0; i < 2; ++i) {
    const int off = (i * 8 + wave) * 1024 + lane * 16;
    soff[i] = off;
    const int krow = off >> 7, kbin = off & 127;
    kgp[i] = Kp + (size_t)(b * S + krow) * LD + h * 64 + ((kbin ^ ((krow & 7) << 4)) >> 1);
    const int d = off >> 8, vbin = off & 255;
    vgp[i] = VTp + (size_t)((b * 16 + h) * 64 + d) * S + ((vbin ^ ((d & 7) << 4)) >> 1);
  }

  bf16x8 qf[2];
#pragma unroll
  for (int ks = 0; ks < 2; ++ks)
    qf[ks] = *reinterpret_cast<const bf16x8*>(
        Qp + (size_t)(b * S + q0 + wave * 16 + l15) * LD + h * 64 + ks * 32 + lhi * 8);

  // ================= pass A: l = sum over kv of exp(s - 15) =================
  // K tile for kt lives in region (kt&1): 0 -> Kt, 1 -> Vt. One barrier/tile.
  bf16x8 kreg[2];
  float mnext;
#pragma unroll
  for (int i = 0; i < 2; ++i) kreg[i] = *reinterpret_cast<const bf16x8*>(kgp[i]);
  mnext = (t < KB) ? (mrow[t] ? 0.f : 1.f) : 0.f;
#pragma unroll
  for (int i = 0; i < 2; ++i)
    *reinterpret_cast<bf16x8*>((char*)Kt + soff[i]) = kreg[i];
  if (t < KB) msk2[0][t] = mnext;
  __syncthreads();

  float lpart = 0.f;
  for (int kt = 0; kt < NT; ++kt) {
    const int kv0 = kt * KB;
    if (kt + 1 < NT) {  // issue-early: next K tile -> regs
#pragma unroll
      for (int i = 0; i < 2; ++i)
        kreg[i] = *reinterpret_cast<const bf16x8*>(kgp[i] + (size_t)(kv0 + KB) * LD);
      mnext = (t < KB) ? (mrow[kv0 + KB + t] ? 0.f : 1.f) : 0.f;
    }
    const char* kb = (kt & 1) ? (const char*)Vt : (const char*)Kt;
    const float* mc = msk2[kt & 1];
    f32x4 sa[8];
#pragma unroll
    for (int n = 0; n < 8; ++n) sa[n] = z4;
    __builtin_amdgcn_s_setprio(1);
#pragma unroll
    for (int ks = 0; ks < 2; ++ks)
#pragma unroll
      for (int n = 0; n < 8; ++n) {
        const int krow = n * 16 + l15;
        bf16x8 kf = *reinterpret_cast<const bf16x8*>(
            kb + krow * 128 + ((ks * 64 + lhi * 16) ^ ((krow & 7) << 4)));
        sa[n] = mfma16(kf, qf[ks], sa[n]);
      }
    __builtin_amdgcn_s_setprio(0);
#pragma unroll
    for (int n = 0; n < 8; ++n)
#pragma unroll
      for (int r = 0; r < 4; ++r)
        lpart += __expf(sa[n][r] - 15.f) * mc[n * 16 + lhi * 4 + r];
    if (kt + 1 < NT) {  // write next tile into the OTHER region (no read conflict)
      char* kbn = ((kt + 1) & 1) ? (char*)Vt : (char*)Kt;
#pragma unroll
      for (int i = 0; i < 2; ++i)
        *reinterpret_cast<bf16x8*>(kbn + soff[i]) = kreg[i];
      if (t < KB) msk2[(kt + 1) & 1][t] = mnext;
    }
    __syncthreads();  // staging visible + this tile's reads done
  }
  lpart += __shfl_xor(lpart, 16);
  lpart += __shfl_xor(lpart, 32);
  const float il = 1.f / lpart;  // for q-row = wave*16 + l15

  // ================= pass B: probs + PV =================
  f32x4 oa[4];
#pragma unroll
  for (int n = 0; n < 4; ++n) oa[n] = z4;
  float* pbase = probs + ((size_t)(b * 16 + h) * S + q0 + wave * 16 + l15) * S;
  const int prw = wave * 16 + l15;

  bf16x8 vreg[2];
#pragma unroll
  for (int i = 0; i < 2; ++i) {
    kreg[i] = *reinterpret_cast<const bf16x8*>(kgp[i]);
    vreg[i] = *reinterpret_cast<const bf16x8*>(vgp[i]);
  }
  mnext = (t < KB) ? (mrow[t] ? 0.f : 1.f) : 0.f;
  // pass A's last barrier guarantees no wave is still reading Kt/Vt
#pragma unroll
  for (int i = 0; i < 2; ++i) {
    *reinterpret_cast<bf16x8*>((char*)Kt + soff[i]) = kreg[i];
    *reinterpret_cast<bf16x8*>((char*)Vt + soff[i]) = vreg[i];
  }
  if (t < KB) msk2[0][t] = mnext;
  __syncthreads();

  for (int kt = 0; kt < NT; ++kt) {
    const int kv0 = kt * KB;
    if (kt + 1 < NT) {  // issue-early: next K+V tiles -> regs
#pragma unroll
      for (int i = 0; i < 2; ++i) {
        kreg[i] = *reinterpret_cast<const bf16x8*>(kgp[i] + (size_t)(kv0 + KB) * LD);
        vreg[i] = *reinterpret_cast<const bf16x8*>(vgp[i] + kv0 + KB);
      }
      mnext = (t < KB) ? (mrow[kv0 + KB + t] ? 0.f : 1.f) : 0.f;
    }

    f32x4 sa[8];
#pragma unroll
    for (int n = 0; n < 8; ++n) sa[n] = z4;
    __builtin_amdgcn_s_setprio(1);
#pragma unroll
    for (int ks = 0; ks < 2; ++ks)
#pragma unroll
      for (int n = 0; n < 8; ++n) {
        const int krow = n * 16 + l15;
        bf16x8 kf = *reinterpret_cast<const bf16x8*>(
            (char*)Kt + krow * 128 + ((ks * 64 + lhi * 16) ^ ((krow & 7) << 4)));
        sa[n] = mfma16(kf, qf[ks], sa[n]);
      }
    __builtin_amdgcn_s_setprio(0);

#pragma unroll
    for (int n = 0; n < 8; ++n) {
      f32x4 pn;
#pragma unroll
      for (int r = 0; r < 4; ++r)
        pn[r] = __expf(sa[n][r] - 15.f) * msk2[0][n * 16 + lhi * 4 + r] * il;
      *reinterpret_cast<f32x4*>(pbase + kv0 + n * 16 + lhi * 4) = pn;
      bf16x4 pb;
      pb[0] = (bf16)pn[0]; pb[1] = (bf16)pn[1];
      pb[2] = (bf16)pn[2]; pb[3] = (bf16)pn[3];
      *reinterpret_cast<bf16x4*>(
          (char*)P + prw * 256 + ((n * 32 + lhi * 8) ^ ((prw & 7) << 4))) = pb;
    }
    __builtin_amdgcn_s_setprio(1);
#pragma unroll
    for (int ks = 0; ks < 4; ++ks) {
      bf16x8 pf = *reinterpret_cast<const bf16x8*>(
          (char*)P + prw * 256 + ((ks * 64 + lhi * 16) ^ ((prw & 7) << 4)));
#pragma unroll
      for (int nn = 0; nn < 4; ++nn) {
        const int vr = nn * 16 + l15;
        bf16x8 vf = *reinterpret_cast<const bf16x8*>(
            (char*)Vt + vr * 256 + ((ks * 64 + lhi * 16) ^ ((vr & 7) << 4)));
        oa[nn] = mfma16(pf, vf, oa[nn]);
      }
    }
    __builtin_amdgcn_s_setprio(0);
    __syncthreads();  // Kt/Vt reads done
    if (kt + 1 < NT) {  // write-late
#pragma unroll
      for (int i = 0; i < 2; ++i) {
        *reinterpret_cast<bf16x8*>((char*)Kt + soff[i]) = kreg[i];
        *reinterpret_cast<bf16x8*>((char*)Vt + soff[i]) = vreg[i];
      }
      if (t < KB) msk2[0][t] = mnext;
    }
    __syncthreads();  // staging visible
  }

#pragma unroll
  for (int nn = 0; nn < 4; ++nn)
#pragma unroll
    for (int r = 0; r < 4; ++r)
      Ob[(size_t)(b * S + q0 + wave * 16 + lhi * 4 + r) * 1024 + h * 64 + nn * 16 + l15] =
          (bf16)oa[nn][r];
}

// ---------------- launch ----------------
extern "C" void kernel_launch(void* const* d_in, const int* in_sizes, int n_in,
                              void* d_out, int out_size, void* d_ws, size_t ws_size,
                              hipStream_t stream) {
  const float* src = (const float*)d_in[0];
  const int* mask = (const int*)d_in[1];
  const float* Wq = (const float*)d_in[2];
  const float* bq = (const float*)d_in[3];
  const float* Wk = (const float*)d_in[4];
  const float* bk = (const float*)d_in[5];
  const float* Wv = (const float*)d_in[6];
  const float* bv = (const float*)d_in[7];
  const float* Wo = (const float*)d_in[8];
  const float* bo = (const float*)d_in[9];
  const float* W1 = (const float*)d_in[10];
  const float* b1 = (const float*)d_in[11];
  const float* W2 = (const float*)d_in[12];
  const float* b2 = (const float*)d_in[13];
  const float* ln1g = (const float*)d_in[14];
  const float* ln1b = (const float*)d_in[15];
  const float* ln2g = (const float*)d_in[16];
  const float* ln2b = (const float*)d_in[17];

  float* out0 = (float*)d_out;                       // [2,2048,1024]
  float* probs = (float*)d_out + (size_t)4194304;    // [2,16,2048,2048]

  char* w = (char*)d_ws;
  const size_t MB = 1u << 20;
  bf16* wqkv = (bf16*)(w);              // [3072,1024] rows: Wq|Wk|Wv (6MB)
  bf16* wob = (bf16*)(w + 6 * MB);      // [1024,1024]
  bf16* w1b = (bf16*)(w + 8 * MB);      // [4096,1024]
  bf16* w2b = (bf16*)(w + 16 * MB);     // [1024,4096]
  bf16* xn = (bf16*)(w + 24 * MB);      // [4096,1024]
  bf16* QKV = (bf16*)(w + 32 * MB);     // [4096,3072] (24MB)
  bf16* Ob = (bf16*)(w + 56 * MB);      // [4096,1024]
  bf16* hb = (bf16*)(w + 32 * MB);      // [4096,4096] reuse (QKV dead by then)
  bf16* VT = (bf16*)(w + 64 * MB);      // [2,16,64,2048] (8MB); dead after attn
  float* s2 = (float*)(w + 64 * MB);    // [4096,1024] fp32 (16MB) overlays VT
  float* bqkv = (float*)(w + 80 * MB);  // [3072]

  // fused weight conversion + bias concat (1 launch)
  cvt_all<<<12291, 256, 0, stream>>>(Wq, Wk, Wv, Wo, W1, W2, bq, bk, bv,
                                     wqkv, wob, w1b, w2b, bqkv);

  // LN1
  ln_bf16<<<4096, 256, 0, stream>>>(src, ln1g, ln1b, xn);
  // fused QKV projection (Q part pre-scaled by 1/8)
  gemm_bt<true, false, false, true><<<dim3(24, 32), 256, 0, stream>>>(
      xn, wqkv, bqkv, nullptr, QKV, 4096, 3072, 1024);
  // V transpose for attn staging
  tr_v<<<dim3(32, 16, 2), 256, 0, stream>>>(QKV, VT);
  // fused attention (QBLK=128, 8 waves)
  attn_fused2<<<dim3(16, 16, 2), 512, 0, stream>>>(
      QKV, QKV + 1024, VT, mask, probs, Ob);
  // Wo + residual(src) -> s2 (fp32)
  gemm_bt<false, false, true, false><<<dim3(8, 32), 256, 0, stream>>>(
      Ob, wob, bo, src, s2, 4096, 1024, 1024);
  // LN2
  ln_bf16<<<4096, 256, 0, stream>>>(s2, ln2g, ln2b, xn);
  // FFN1 + ReLU
  gemm_bt<true, true, false, false><<<dim3(32, 32), 256, 0, stream>>>(
      xn, w1b, b1, nullptr, hb, 4096, 4096, 1024);
  // FFN2 + residual(s2) -> out0
  gemm_bt<false, false, true, false><<<dim3(8, 32), 256, 0, stream>>>(
      hb, w2b, b2, s2, out0, 4096, 1024, 4096);

  (void)in_sizes; (void)n_in; (void)out_size; (void)ws_size;
}

// Round 10
// 424.387 us; speedup vs baseline: 1.0633x; 1.0246x over previous
//
#include <hip/hip_runtime.h>
#include <math.h>

typedef __bf16 bf16;
typedef __bf16 bf16x4 __attribute__((ext_vector_type(4)));
typedef __bf16 bf16x8 __attribute__((ext_vector_type(8)));
typedef float f32x4 __attribute__((ext_vector_type(4)));

__device__ __forceinline__ f32x4 mfma16(bf16x8 a, bf16x8 b, f32x4 c) {
  return __builtin_amdgcn_mfma_f32_16x16x32_bf16(a, b, c, 0, 0, 0);
}

__device__ __forceinline__ void gload_lds16(const void* g, void* l) {
  __builtin_amdgcn_global_load_lds((__attribute__((address_space(1))) void*)(g),
                                   (__attribute__((address_space(3))) void*)(l),
                                   16, 0, 0);
}

// ---------------- fused weight conversion + bias concat (1 launch) ----------
__global__ __launch_bounds__(256)
void cvt_all(const float* __restrict__ Wq, const float* __restrict__ Wk,
             const float* __restrict__ Wv, const float* __restrict__ Wo,
             const float* __restrict__ W1, const float* __restrict__ W2,
             const float* __restrict__ bq, const float* __restrict__ bk,
             const float* __restrict__ bv, bf16* __restrict__ wqkv,
             bf16* __restrict__ wob, bf16* __restrict__ w1b,
             bf16* __restrict__ w2b, float* __restrict__ bqkv) {
  const int i = blockIdx.x * 256 + threadIdx.x;
  if (i < 3145728) {
    float4 v;
    bf16* dst;
    size_t di;
    if (i < 262144) { v = ((const float4*)Wq)[i]; dst = wqkv; di = i; }
    else if (i < 524288) { v = ((const float4*)Wk)[i - 262144]; dst = wqkv; di = i; }
    else if (i < 786432) { v = ((const float4*)Wv)[i - 524288]; dst = wqkv; di = i; }
    else if (i < 1048576) { v = ((const float4*)Wo)[i - 786432]; dst = wob; di = i - 786432; }
    else if (i < 2097152) { v = ((const float4*)W1)[i - 1048576]; dst = w1b; di = i - 1048576; }
    else { v = ((const float4*)W2)[i - 2097152]; dst = w2b; di = i - 2097152; }
    bf16x4 o;
    o[0] = (bf16)v.x; o[1] = (bf16)v.y; o[2] = (bf16)v.z; o[3] = (bf16)v.w;
    reinterpret_cast<bf16x4*>(dst)[di] = o;
  } else {
    const int j = i - 3145728;  // 0..767
    const float* s = (j < 256) ? bq : ((j < 512) ? bk : bv);
    reinterpret_cast<float4*>(bqkv)[j] = reinterpret_cast<const float4*>(s)[j & 255];
  }
}

// ---------------- LayerNorm fp32 -> bf16, D=1024, block=256 ----------------
__global__ __launch_bounds__(256)
void ln_bf16(const float* __restrict__ x, const float* __restrict__ g,
             const float* __restrict__ bta, bf16* __restrict__ y) {
  const int row = blockIdx.x, t = threadIdx.x;
  const float4 v = reinterpret_cast<const float4*>(x)[(size_t)row * 256 + t];
  float s1 = v.x + v.y + v.z + v.w;
  float s2 = v.x * v.x + v.y * v.y + v.z * v.z + v.w * v.w;
#pragma unroll
  for (int m = 1; m < 64; m <<= 1) {
    s1 += __shfl_xor(s1, m);
    s2 += __shfl_xor(s2, m);
  }
  __shared__ float red[8];
  if ((t & 63) == 0) { red[(t >> 6) * 2] = s1; red[(t >> 6) * 2 + 1] = s2; }
  __syncthreads();
  s1 = red[0] + red[2] + red[4] + red[6];
  s2 = red[1] + red[3] + red[5] + red[7];
  const float mu = s1 * (1.f / 1024.f);
  const float rs = rsqrtf(s2 * (1.f / 1024.f) - mu * mu + 1e-5f);
  const float4 gv = reinterpret_cast<const float4*>(g)[t];
  const float4 bv = reinterpret_cast<const float4*>(bta)[t];
  bf16x4 o;
  o[0] = (bf16)((v.x - mu) * rs * gv.x + bv.x);
  o[1] = (bf16)((v.y - mu) * rs * gv.y + bv.y);
  o[2] = (bf16)((v.z - mu) * rs * gv.z + bv.z);
  o[3] = (bf16)((v.w - mu) * rs * gv.w + bv.w);
  reinterpret_cast<bf16x4*>(y)[(size_t)row * 256 + t] = o;
}

// ---------------- V transpose: QKV V-part -> VT[b,h,d,s] ----------------
__global__ __launch_bounds__(256)
void tr_v(const bf16* __restrict__ QKV, bf16* __restrict__ VT) {
  __shared__ bf16 T[64 * 80];
  const int t = threadIdx.x;
  const int sb = blockIdx.x * 64, h = blockIdx.y, b = blockIdx.z;
  const int srow = t >> 2, c16 = t & 3;
  const bf16* src = QKV + (size_t)(b * 2048 + sb + srow) * 3072 + 2048 + h * 64 + c16 * 16;
  bf16x8 a0 = *reinterpret_cast<const bf16x8*>(src);
  bf16x8 a1 = *reinterpret_cast<const bf16x8*>(src + 8);
  *reinterpret_cast<bf16x8*>(&T[srow * 80 + c16 * 16]) = a0;
  *reinterpret_cast<bf16x8*>(&T[srow * 80 + c16 * 16 + 8]) = a1;
  __syncthreads();
  const int drow = t >> 2, sq = t & 3;
  bf16x8 o0, o1;
#pragma unroll
  for (int j = 0; j < 8; ++j) o0[j] = T[(sq * 16 + j) * 80 + drow];
#pragma unroll
  for (int j = 0; j < 8; ++j) o1[j] = T[(sq * 16 + 8 + j) * 80 + drow];
  bf16* dst = VT + ((size_t)(b * 16 + h) * 64 + drow) * 2048 + sb + sq * 16;
  *reinterpret_cast<bf16x8*>(dst) = o0;
  *reinterpret_cast<bf16x8*>(dst + 8) = o1;
}

// ---------------- GEMM: C[M,N] = act(A[M,K] @ Bw[N,K]^T + bias) (+res) --------
// TM x 128 tile (TM = 128 or 64), BK=32, 4 waves, 16x16x32 MFMA, glds w16,
// XCD swizzle, counted-vmcnt depth-2 pipeline (T4), 3 LDS buffers.
// QSC: scale output by 0.125*log2(e) for col blocks < 1024 (Q pre-scale for
// the exp2-based attn softmax).
template <int TM, bool OUT_BF16, bool RELU, bool RES, bool QSC>
__global__ __launch_bounds__(256)
void gemm_bt(const bf16* __restrict__ A, const bf16* __restrict__ Bw,
             const float* __restrict__ bias, const float* __restrict__ res,
             void* __restrict__ Cout, int M, int N, int K) {
  constexpr int MR = TM / 32;   // per-wave m-frags (4 or 2)
  constexpr int ACH = TM / 64;  // A staging chunks (2 or 1)
  __shared__ bf16 As[3][TM * 32];
  __shared__ bf16 Bs[3][128 * 32];
  const int t = threadIdx.x, wave = t >> 6, lane = t & 63;
  const int l15 = lane & 15, lhi = lane >> 4;
  const int nwg = gridDim.x * gridDim.y;
  const int orig = blockIdx.y * gridDim.x + blockIdx.x;
  const int wgid = (orig & 7) * (nwg >> 3) + (orig >> 3);
  const int bx = wgid % gridDim.x, by = wgid / gridDim.x;
  const int m0 = by * TM, n0 = bx * 128;
  const int wm = (wave >> 1) * (TM / 2), wn = (wave & 1) * 64;
  const f32x4 z4 = {0.f, 0.f, 0.f, 0.f};
  f32x4 acc[MR][4];
#pragma unroll
  for (int m = 0; m < MR; ++m)
#pragma unroll
    for (int n = 0; n < 4; ++n) acc[m][n] = z4;

  // staging coords: chunk i covers bytes [i*4096, (i+1)*4096), 64B rows
  int soff[2], srow[2], scol[2];
#pragma unroll
  for (int i = 0; i < 2; ++i) {
    soff[i] = (i * 4 + wave) * 1024 + lane * 16;
    srow[i] = soff[i] >> 6;
    scol[i] = (soff[i] & 63) >> 1;
  }

#define GEMM_STAGE(k0, bb)                                                    \
  do {                                                                        \
    _Pragma("unroll")                                                         \
    for (int i = 0; i < ACH; ++i)                                             \
      gload_lds16(A + (size_t)(m0 + srow[i]) * K + (k0) + scol[i],            \
                  (char*)As[bb] + soff[i]);                                   \
    _Pragma("unroll")                                                         \
    for (int i = 0; i < 2; ++i)                                               \
      gload_lds16(Bw + (size_t)(n0 + srow[i]) * K + (k0) + scol[i],           \
                  (char*)Bs[bb] + soff[i]);                                   \
  } while (0)

  const int nt = K >> 5;
  GEMM_STAGE(0, 0);
  GEMM_STAGE(32, 1);
  if constexpr (TM == 128)
    asm volatile("s_waitcnt vmcnt(4)" ::: "memory");  // tile 0 landed
  else
    asm volatile("s_waitcnt vmcnt(3)" ::: "memory");
  __builtin_amdgcn_s_barrier();

  for (int kt = 0; kt < nt; ++kt) {
    if (kt + 2 < nt) GEMM_STAGE((kt + 2) * 32, (kt + 2) % 3);
    const bf16* Ac = As[kt % 3];
    const bf16* Bc = Bs[kt % 3];
    bf16x8 af[MR], bfr[4];
#pragma unroll
    for (int m = 0; m < MR; ++m)
      af[m] = *reinterpret_cast<const bf16x8*>(&Ac[(wm + m * 16 + l15) * 32 + lhi * 8]);
#pragma unroll
    for (int n = 0; n < 4; ++n)
      bfr[n] = *reinterpret_cast<const bf16x8*>(&Bc[(wn + n * 16 + l15) * 32 + lhi * 8]);
    __builtin_amdgcn_s_setprio(1);
#pragma unroll
    for (int m = 0; m < MR; ++m)
#pragma unroll
      for (int n = 0; n < 4; ++n) acc[m][n] = mfma16(af[m], bfr[n], acc[m][n]);
    __builtin_amdgcn_s_setprio(0);
    if (kt + 1 < nt) {
      if (kt + 2 < nt) {
        if constexpr (TM == 128)
          asm volatile("s_waitcnt vmcnt(4)" ::: "memory");  // t+1 landed
        else
          asm volatile("s_waitcnt vmcnt(3)" ::: "memory");
      } else {
        asm volatile("s_waitcnt vmcnt(0)" ::: "memory");
      }
      __builtin_amdgcn_s_barrier();
    }
  }
#undef GEMM_STAGE

  const float sc = (QSC && n0 < 1024) ? 0.18033688011112042f : 1.0f;  // 0.125*log2(e)
#pragma unroll
  for (int m = 0; m < MR; ++m) {
    const int row_base = m0 + wm + m * 16 + lhi * 4;
#pragma unroll
    for (int n = 0; n < 4; ++n) {
      const int col = n0 + wn + n * 16 + l15;
      const float bv = bias[col];
#pragma unroll
      for (int r = 0; r < 4; ++r) {
        const int row = row_base + r;
        float v = (acc[m][n][r] + bv) * sc;
        if (RELU) v = v > 0.f ? v : 0.f;
        if (RES) v += res[(size_t)row * N + col];
        if (OUT_BF16)
          ((bf16*)Cout)[(size_t)row * N + col] = (bf16)v;
        else
          ((float*)Cout)[(size_t)row * N + col] = v;
      }
    }
  }
}

// ---------------- Fused attention: QBLK=128, 8 waves, T14 ----------------
// grid 512 blocks (XCD-swizzled), 8 waves, 128 q rows/block (16/wave).
// Swapped QK^T: mfma(K, Q) -> lane holds q-row = l15, kv = n*16+lhi*4+r.
// Q pre-scaled by 0.125*log2e -> scores in log2 domain; p = exp2(s) (bare
// v_exp_f32, no shift/mul). P stored UNNORMALIZED (bf16 is scale-free);
// O rescaled by il in epilogue; probs = p*il, non-temporal stores (probs are
// write-once -> keep K/V in L2). Pass A: K ping-pongs Kt/Vt, 1 barrier/tile.
__global__ __launch_bounds__(512)
void attn_fused2(const bf16* __restrict__ Qp, const bf16* __restrict__ Kp,
                 const bf16* __restrict__ VTp, const int* __restrict__ mask,
                 float* __restrict__ probs, bf16* __restrict__ Ob) {
  constexpr int S = 2048, LD = 3072, KB = 128, NT = S / KB;
  __shared__ bf16 Kt[KB * 64];    // [128 kv][64 d], rows 128B, swizzled (16KB)
  __shared__ bf16 Vt[64 * KB];    // pass A: K ping buffer; pass B: [64 d][128 kv]
  __shared__ bf16 P[128 * KB];    // [128 q][128 kv], rows 256B, swizzled (32KB)
  __shared__ float msk2[2][KB];
  const int t = threadIdx.x, wave = t >> 6, lane = t & 63;
  const int l15 = lane & 15, lhi = lane >> 4;
  const int flat = blockIdx.x + 16 * (blockIdx.y + 16 * blockIdx.z);
  const int wg = (flat & 7) * 64 + (flat >> 3);
  const int q0 = (wg & 15) * 128, h = (wg >> 4) & 15, b = wg >> 8;
  const int* mrow = mask + b * S;
  const f32x4 z4 = {0.f, 0.f, 0.f, 0.f};

  // per-thread staging map: 2 chunks of 16B each for K and for V (512 thr)
  const bf16* kgp[2];
  const bf16* vgp[2];
  int soff[2];
#pragma unroll
  for (int i = 0; i < 2; ++i) {
    const int off = (i * 8 + wave) * 1024 + lane * 16;
    soff[i] = off;
    const int krow = off >> 7, kbin = off & 127;
    kgp[i] = Kp + (size_t)(b * S + krow) * LD + h * 64 + ((kbin ^ ((krow & 7) << 4)) >> 1);
    const int d = off >> 8, vbin = off & 255;
    vgp[i] = VTp + (size_t)((b * 16 + h) * 64 + d) * S + ((vbin ^ ((d & 7) << 4)) >> 1);
  }

  bf16x8 qf[2];
#pragma unroll
  for (int ks = 0; ks < 2; ++ks)
    qf[ks] = *reinterpret_cast<const bf16x8*>(
        Qp + (size_t)(b * S + q0 + wave * 16 + l15) * LD + h * 64 + ks * 32 + lhi * 8);

  // ================= pass A: l = sum over kv of exp2(s) =================
  bf16x8 kreg[2];
  float mnext;
#pragma unroll
  for (int i = 0; i < 2; ++i) kreg[i] = *reinterpret_cast<const bf16x8*>(kgp[i]);
  mnext = (t < KB) ? (mrow[t] ? 0.f : 1.f) : 0.f;
#pragma unroll
  for (int i = 0; i < 2; ++i)
    *reinterpret_cast<bf16x8*>((char*)Kt + soff[i]) = kreg[i];
  if (t < KB) msk2[0][t] = mnext;
  __syncthreads();

  float lpart = 0.f;
  for (int kt = 0; kt < NT; ++kt) {
    const int kv0 = kt * KB;
    if (kt + 1 < NT) {  // issue-early: next K tile -> regs
#pragma unroll
      for (int i = 0; i < 2; ++i)
        kreg[i] = *reinterpret_cast<const bf16x8*>(kgp[i] + (size_t)(kv0 + KB) * LD);
      mnext = (t < KB) ? (mrow[kv0 + KB + t] ? 0.f : 1.f) : 0.f;
    }
    const char* kb = (kt & 1) ? (const char*)Vt : (const char*)Kt;
    const float* mc = msk2[kt & 1];
    f32x4 sa[8];
#pragma unroll
    for (int n = 0; n < 8; ++n) sa[n] = z4;
    __builtin_amdgcn_s_setprio(1);
#pragma unroll
    for (int ks = 0; ks < 2; ++ks)
#pragma unroll
      for (int n = 0; n < 8; ++n) {
        const int krow = n * 16 + l15;
        bf16x8 kf = *reinterpret_cast<const bf16x8*>(
            kb + krow * 128 + ((ks * 64 + lhi * 16) ^ ((krow & 7) << 4)));
        sa[n] = mfma16(kf, qf[ks], sa[n]);
      }
    __builtin_amdgcn_s_setprio(0);
#pragma unroll
    for (int n = 0; n < 8; ++n)
#pragma unroll
      for (int r = 0; r < 4; ++r)
        lpart += __builtin_exp2f(sa[n][r]) * mc[n * 16 + lhi * 4 + r];
    if (kt + 1 < NT) {  // write next tile into the OTHER region
      char* kbn = ((kt + 1) & 1) ? (char*)Vt : (char*)Kt;
#pragma unroll
      for (int i = 0; i < 2; ++i)
        *reinterpret_cast<bf16x8*>(kbn + soff[i]) = kreg[i];
      if (t < KB) msk2[(kt + 1) & 1][t] = mnext;
    }
    __syncthreads();  // staging visible + this tile's reads done
  }
  lpart += __shfl_xor(lpart, 16);
  lpart += __shfl_xor(lpart, 32);
  const float il = 1.f / lpart;  // for q-row = wave*16 + l15

  // ================= pass B: probs + PV =================
  f32x4 oa[4];
#pragma unroll
  for (int n = 0; n < 4; ++n) oa[n] = z4;
  float* pbase = probs + ((size_t)(b * 16 + h) * S + q0 + wave * 16 + l15) * S;
  const int prw = wave * 16 + l15;

  bf16x8 vreg[2];
#pragma unroll
  for (int i = 0; i < 2; ++i) {
    kreg[i] = *reinterpret_cast<const bf16x8*>(kgp[i]);
    vreg[i] = *reinterpret_cast<const bf16x8*>(vgp[i]);
  }
  mnext = (t < KB) ? (mrow[t] ? 0.f : 1.f) : 0.f;
#pragma unroll
  for (int i = 0; i < 2; ++i) {
    *reinterpret_cast<bf16x8*>((char*)Kt + soff[i]) = kreg[i];
    *reinterpret_cast<bf16x8*>((char*)Vt + soff[i]) = vreg[i];
  }
  if (t < KB) msk2[0][t] = mnext;
  __syncthreads();

  for (int kt = 0; kt < NT; ++kt) {
    const int kv0 = kt * KB;
    if (kt + 1 < NT) {  // issue-early: next K+V tiles -> regs
#pragma unroll
      for (int i = 0; i < 2; ++i) {
        kreg[i] = *reinterpret_cast<const bf16x8*>(kgp[i] + (size_t)(kv0 + KB) * LD);
        vreg[i] = *reinterpret_cast<const bf16x8*>(vgp[i] + kv0 + KB);
      }
      mnext = (t < KB) ? (mrow[kv0 + KB + t] ? 0.f : 1.f) : 0.f;
    }

    f32x4 sa[8];
#pragma unroll
    for (int n = 0; n < 8; ++n) sa[n] = z4;
    __builtin_amdgcn_s_setprio(1);
#pragma unroll
    for (int ks = 0; ks < 2; ++ks)
#pragma unroll
      for (int n = 0; n < 8; ++n) {
        const int krow = n * 16 + l15;
        bf16x8 kf = *reinterpret_cast<const bf16x8*>(
            (char*)Kt + krow * 128 + ((ks * 64 + lhi * 16) ^ ((krow & 7) << 4)));
        sa[n] = mfma16(kf, qf[ks], sa[n]);
      }
    __builtin_amdgcn_s_setprio(0);

#pragma unroll
    for (int n = 0; n < 8; ++n) {
      f32x4 praw, pn;
#pragma unroll
      for (int r = 0; r < 4; ++r) {
        praw[r] = __builtin_exp2f(sa[n][r]) * msk2[0][n * 16 + lhi * 4 + r];
        pn[r] = praw[r] * il;
      }
      __builtin_nontemporal_store(pn, reinterpret_cast<f32x4*>(pbase + kv0 + n * 16 + lhi * 4));
      bf16x4 pb;
      pb[0] = (bf16)praw[0]; pb[1] = (bf16)praw[1];
      pb[2] = (bf16)praw[2]; pb[3] = (bf16)praw[3];
      *reinterpret_cast<bf16x4*>(
          (char*)P + prw * 256 + ((n * 32 + lhi * 8) ^ ((prw & 7) << 4))) = pb;
    }
    __builtin_amdgcn_s_setprio(1);
#pragma unroll
    for (int ks = 0; ks < 4; ++ks) {
      bf16x8 pf = *reinterpret_cast<const bf16x8*>(
          (char*)P + prw * 256 + ((ks * 64 + lhi * 16) ^ ((prw & 7) << 4)));
#pragma unroll
      for (int nn = 0; nn < 4; ++nn) {
        const int vr = nn * 16 + l15;
        bf16x8 vf = *reinterpret_cast<const bf16x8*>(
            (char*)Vt + vr * 256 + ((ks * 64 + lhi * 16) ^ ((vr & 7) << 4)));
        oa[nn] = mfma16(pf, vf, oa[nn]);
      }
    }
    __builtin_amdgcn_s_setprio(0);
    __syncthreads();  // Kt/Vt reads done
    if (kt + 1 < NT) {  // write-late
#pragma unroll
      for (int i = 0; i < 2; ++i) {
        *reinterpret_cast<bf16x8*>((char*)Kt + soff[i]) = kreg[i];
        *reinterpret_cast<bf16x8*>((char*)Vt + soff[i]) = vreg[i];
      }
      if (t < KB) msk2[0][t] = mnext;
    }
    __syncthreads();  // staging visible
  }

  // O epilogue: rescale unnormalized accumulation by il of the proper q-row.
  float il4[4];
#pragma unroll
  for (int r = 0; r < 4; ++r) il4[r] = __shfl(il, lhi * 4 + r);
#pragma unroll
  for (int nn = 0; nn < 4; ++nn)
#pragma unroll
    for (int r = 0; r < 4; ++r)
      Ob[(size_t)(b * S + q0 + wave * 16 + lhi * 4 + r) * 1024 + h * 64 + nn * 16 + l15] =
          (bf16)(oa[nn][r] * il4[r]);
}

// ---------------- launch ----------------
extern "C" void kernel_launch(void* const* d_in, const int* in_sizes, int n_in,
                              void* d_out, int out_size, void* d_ws, size_t ws_size,
                              hipStream_t stream) {
  const float* src = (const float*)d_in[0];
  const int* mask = (const int*)d_in[1];
  const float* Wq = (const float*)d_in[2];
  const float* bq = (const float*)d_in[3];
  const float* Wk = (const float*)d_in[4];
  const float* bk = (const float*)d_in[5];
  const float* Wv = (const float*)d_in[6];
  const float* bv = (const float*)d_in[7];
  const float* Wo = (const float*)d_in[8];
  const float* bo = (const float*)d_in[9];
  const float* W1 = (const float*)d_in[10];
  const float* b1 = (const float*)d_in[11];
  const float* W2 = (const float*)d_in[12];
  const float* b2 = (const float*)d_in[13];
  const float* ln1g = (const float*)d_in[14];
  const float* ln1b = (const float*)d_in[15];
  const float* ln2g = (const float*)d_in[16];
  const float* ln2b = (const float*)d_in[17];

  float* out0 = (float*)d_out;                       // [2,2048,1024]
  float* probs = (float*)d_out + (size_t)4194304;    // [2,16,2048,2048]

  char* w = (char*)d_ws;
  const size_t MB = 1u << 20;
  bf16* wqkv = (bf16*)(w);              // [3072,1024] rows: Wq|Wk|Wv (6MB)
  bf16* wob = (bf16*)(w + 6 * MB);      // [1024,1024]
  bf16* w1b = (bf16*)(w + 8 * MB);      // [4096,1024]
  bf16* w2b = (bf16*)(w + 16 * MB);     // [1024,4096]
  bf16* xn = (bf16*)(w + 24 * MB);      // [4096,1024]
  bf16* QKV = (bf16*)(w + 32 * MB);     // [4096,3072] (24MB)
  bf16* Ob = (bf16*)(w + 56 * MB);      // [4096,1024]
  bf16* hb = (bf16*)(w + 32 * MB);      // [4096,4096] reuse (QKV dead by then)
  bf16* VT = (bf16*)(w + 64 * MB);      // [2,16,64,2048] (8MB); dead after attn
  float* s2 = (float*)(w + 64 * MB);    // [4096,1024] fp32 (16MB) overlays VT
  float* bqkv = (float*)(w + 80 * MB);  // [3072]

  // fused weight conversion + bias concat (1 launch)
  cvt_all<<<12291, 256, 0, stream>>>(Wq, Wk, Wv, Wo, W1, W2, bq, bk, bv,
                                     wqkv, wob, w1b, w2b, bqkv);

  // LN1
  ln_bf16<<<4096, 256, 0, stream>>>(src, ln1g, ln1b, xn);
  // fused QKV projection (Q part pre-scaled by 0.125*log2e)
  gemm_bt<128, true, false, false, true><<<dim3(24, 32), 256, 0, stream>>>(
      xn, wqkv, bqkv, nullptr, QKV, 4096, 3072, 1024);
  // V transpose for attn staging
  tr_v<<<dim3(32, 16, 2), 256, 0, stream>>>(QKV, VT);
  // fused attention (QBLK=128, 8 waves)
  attn_fused2<<<dim3(16, 16, 2), 512, 0, stream>>>(
      QKV, QKV + 1024, VT, mask, probs, Ob);
  // Wo + residual(src) -> s2 (fp32): 64x128 tile, 512 blocks (2/CU)
  gemm_bt<64, false, false, true, false><<<dim3(8, 64), 256, 0, stream>>>(
      Ob, wob, bo, src, s2, 4096, 1024, 1024);
  // LN2
  ln_bf16<<<4096, 256, 0, stream>>>(s2, ln2g, ln2b, xn);
  // FFN1 + ReLU
  gemm_bt<128, true, true, false, false><<<dim3(32, 32), 256, 0, stream>>>(
      xn, w1b, b1, nullptr, hb, 4096, 4096, 1024);
  // FFN2 + residual(s2) -> out0: 64x128 tile, 512 blocks (2/CU)
  gemm_bt<64, false, false, true, false><<<dim3(8, 64), 256, 0, stream>>>(
      hb, w2b, b2, s2, out0, 4096, 1024, 4096);

  (void)in_sizes; (void)n_in; (void)out_size; (void)ws_size;
}

// Round 11
// 408.610 us; speedup vs baseline: 1.1043x; 1.0386x over previous
//
#include <hip/hip_runtime.h>
#include <math.h>

typedef __bf16 bf16;
typedef __bf16 bf16x4 __attribute__((ext_vector_type(4)));
typedef __bf16 bf16x8 __attribute__((ext_vector_type(8)));
typedef float f32x4 __attribute__((ext_vector_type(4)));

__device__ __forceinline__ f32x4 mfma16(bf16x8 a, bf16x8 b, f32x4 c) {
  return __builtin_amdgcn_mfma_f32_16x16x32_bf16(a, b, c, 0, 0, 0);
}

__device__ __forceinline__ void gload_lds16(const void* g, void* l) {
  __builtin_amdgcn_global_load_lds((__attribute__((address_space(1))) void*)(g),
                                   (__attribute__((address_space(3))) void*)(l),
                                   16, 0, 0);
}

// ---------------- fused weight conversion + bias concat (1 launch) ----------
__global__ __launch_bounds__(256)
void cvt_all(const float* __restrict__ Wq, const float* __restrict__ Wk,
             const float* __restrict__ Wv, const float* __restrict__ Wo,
             const float* __restrict__ W1, const float* __restrict__ W2,
             const float* __restrict__ bq, const float* __restrict__ bk,
             const float* __restrict__ bv, bf16* __restrict__ wqkv,
             bf16* __restrict__ wob, bf16* __restrict__ w1b,
             bf16* __restrict__ w2b, float* __restrict__ bqkv) {
  const int i = blockIdx.x * 256 + threadIdx.x;
  if (i < 3145728) {
    float4 v;
    bf16* dst;
    size_t di;
    if (i < 262144) { v = ((const float4*)Wq)[i]; dst = wqkv; di = i; }
    else if (i < 524288) { v = ((const float4*)Wk)[i - 262144]; dst = wqkv; di = i; }
    else if (i < 786432) { v = ((const float4*)Wv)[i - 524288]; dst = wqkv; di = i; }
    else if (i < 1048576) { v = ((const float4*)Wo)[i - 786432]; dst = wob; di = i - 786432; }
    else if (i < 2097152) { v = ((const float4*)W1)[i - 1048576]; dst = w1b; di = i - 1048576; }
    else { v = ((const float4*)W2)[i - 2097152]; dst = w2b; di = i - 2097152; }
    bf16x4 o;
    o[0] = (bf16)v.x; o[1] = (bf16)v.y; o[2] = (bf16)v.z; o[3] = (bf16)v.w;
    reinterpret_cast<bf16x4*>(dst)[di] = o;
  } else {
    const int j = i - 3145728;  // 0..767
    const float* s = (j < 256) ? bq : ((j < 512) ? bk : bv);
    reinterpret_cast<float4*>(bqkv)[j] = reinterpret_cast<const float4*>(s)[j & 255];
  }
}

// ---------------- LayerNorm fp32 -> bf16, D=1024, block=256 ----------------
__global__ __launch_bounds__(256)
void ln_bf16(const float* __restrict__ x, const float* __restrict__ g,
             const float* __restrict__ bta, bf16* __restrict__ y) {
  const int row = blockIdx.x, t = threadIdx.x;
  const float4 v = reinterpret_cast<const float4*>(x)[(size_t)row * 256 + t];
  float s1 = v.x + v.y + v.z + v.w;
  float s2 = v.x * v.x + v.y * v.y + v.z * v.z + v.w * v.w;
#pragma unroll
  for (int m = 1; m < 64; m <<= 1) {
    s1 += __shfl_xor(s1, m);
    s2 += __shfl_xor(s2, m);
  }
  __shared__ float red[8];
  if ((t & 63) == 0) { red[(t >> 6) * 2] = s1; red[(t >> 6) * 2 + 1] = s2; }
  __syncthreads();
  s1 = red[0] + red[2] + red[4] + red[6];
  s2 = red[1] + red[3] + red[5] + red[7];
  const float mu = s1 * (1.f / 1024.f);
  const float rs = rsqrtf(s2 * (1.f / 1024.f) - mu * mu + 1e-5f);
  const float4 gv = reinterpret_cast<const float4*>(g)[t];
  const float4 bv = reinterpret_cast<const float4*>(bta)[t];
  bf16x4 o;
  o[0] = (bf16)((v.x - mu) * rs * gv.x + bv.x);
  o[1] = (bf16)((v.y - mu) * rs * gv.y + bv.y);
  o[2] = (bf16)((v.z - mu) * rs * gv.z + bv.z);
  o[3] = (bf16)((v.w - mu) * rs * gv.w + bv.w);
  reinterpret_cast<bf16x4*>(y)[(size_t)row * 256 + t] = o;
}

// ---------------- V transpose: QKV V-part -> VT[b,h,d,s] ----------------
__global__ __launch_bounds__(256)
void tr_v(const bf16* __restrict__ QKV, bf16* __restrict__ VT) {
  __shared__ bf16 T[64 * 80];
  const int t = threadIdx.x;
  const int sb = blockIdx.x * 64, h = blockIdx.y, b = blockIdx.z;
  const int srow = t >> 2, c16 = t & 3;
  const bf16* src = QKV + (size_t)(b * 2048 + sb + srow) * 3072 + 2048 + h * 64 + c16 * 16;
  bf16x8 a0 = *reinterpret_cast<const bf16x8*>(src);
  bf16x8 a1 = *reinterpret_cast<const bf16x8*>(src + 8);
  *reinterpret_cast<bf16x8*>(&T[srow * 80 + c16 * 16]) = a0;
  *reinterpret_cast<bf16x8*>(&T[srow * 80 + c16 * 16 + 8]) = a1;
  __syncthreads();
  const int drow = t >> 2, sq = t & 3;
  bf16x8 o0, o1;
#pragma unroll
  for (int j = 0; j < 8; ++j) o0[j] = T[(sq * 16 + j) * 80 + drow];
#pragma unroll
  for (int j = 0; j < 8; ++j) o1[j] = T[(sq * 16 + 8 + j) * 80 + drow];
  bf16* dst = VT + ((size_t)(b * 16 + h) * 64 + drow) * 2048 + sb + sq * 16;
  *reinterpret_cast<bf16x8*>(dst) = o0;
  *reinterpret_cast<bf16x8*>(dst + 8) = o1;
}

// ---------------- GEMM v3: 128x256 tile, 8 waves, T2 swizzle, depth-2 -------
// C[M,N] = act(A[M,K] @ Bw[N,K]^T + bias). BK=32, 512 thr (2M x 4N waves),
// 3 LDS buffers (72KB -> 2 blocks/CU), counted vmcnt(3), XCD swizzle,
// XOR-swizzled LDS ((row&3)<<4 on 64B rows; inverse-swizzled glds source).
template <bool RELU, bool QSC>
__global__ __launch_bounds__(512)
void gemm_bt3(const bf16* __restrict__ A, const bf16* __restrict__ Bw,
              const float* __restrict__ bias, bf16* __restrict__ Cout,
              int M, int N, int K) {
  __shared__ bf16 As[3][128 * 32];  // 8KB each, 64B rows, swizzled
  __shared__ bf16 Bs[3][256 * 32];  // 16KB each
  const int t = threadIdx.x, wave = t >> 6, lane = t & 63;
  const int l15 = lane & 15, lhi = lane >> 4;
  const int nwg = gridDim.x * gridDim.y;
  const int orig = blockIdx.y * gridDim.x + blockIdx.x;
  const int wgid = (orig & 7) * (nwg >> 3) + (orig >> 3);
  const int bx = wgid % gridDim.x, by = wgid / gridDim.x;
  const int m0 = by * 128, n0 = bx * 256;
  const int wm = (wave >> 2) * 64, wn = (wave & 3) * 64;
  const f32x4 z4 = {0.f, 0.f, 0.f, 0.f};
  f32x4 acc[4][4];
#pragma unroll
  for (int m = 0; m < 4; ++m)
#pragma unroll
    for (int n = 0; n < 4; ++n) acc[m][n] = z4;

  // staging: A one 16B chunk (d = t*16), B two chunks (d = j*8192 + t*16).
  // dest linear; source col inverse-swizzled.
  const int da = t * 16;
  const int ra = da >> 6, ca = (da & 63) ^ ((ra & 3) << 4);
  const bf16* agp = A + (size_t)(m0 + ra) * K + (ca >> 1);
  int db_[2], rb_[2];
  const bf16* bgp[2];
#pragma unroll
  for (int j = 0; j < 2; ++j) {
    db_[j] = j * 8192 + t * 16;
    rb_[j] = db_[j] >> 6;
    const int cb = (db_[j] & 63) ^ ((rb_[j] & 3) << 4);
    bgp[j] = Bw + (size_t)(n0 + rb_[j]) * K + (cb >> 1);
  }

#define G3_STAGE(k0, bb)                                                      \
  do {                                                                        \
    gload_lds16(agp + (k0), (char*)As[bb] + da);                              \
    gload_lds16(bgp[0] + (k0), (char*)Bs[bb] + db_[0]);                       \
    gload_lds16(bgp[1] + (k0), (char*)Bs[bb] + db_[1]);                       \
  } while (0)

  const int nt = K >> 5;
  G3_STAGE(0, 0);
  G3_STAGE(32, 1);
  asm volatile("s_waitcnt vmcnt(3)" ::: "memory");  // tile 0 landed
  __builtin_amdgcn_s_barrier();

  for (int kt = 0; kt < nt; ++kt) {
    if (kt + 2 < nt) G3_STAGE((kt + 2) * 32, (kt + 2) % 3);
    const char* Ac = (const char*)As[kt % 3];
    const char* Bc = (const char*)Bs[kt % 3];
    bf16x8 af[4], bfr[4];
#pragma unroll
    for (int m = 0; m < 4; ++m) {
      const int row = wm + m * 16 + l15;
      af[m] = *reinterpret_cast<const bf16x8*>(
          Ac + row * 64 + ((lhi * 16) ^ ((row & 3) << 4)));
    }
#pragma unroll
    for (int n = 0; n < 4; ++n) {
      const int row = wn + n * 16 + l15;
      bfr[n] = *reinterpret_cast<const bf16x8*>(
          Bc + row * 64 + ((lhi * 16) ^ ((row & 3) << 4)));
    }
    __builtin_amdgcn_s_setprio(1);
#pragma unroll
    for (int m = 0; m < 4; ++m)
#pragma unroll
      for (int n = 0; n < 4; ++n) acc[m][n] = mfma16(af[m], bfr[n], acc[m][n]);
    __builtin_amdgcn_s_setprio(0);
    if (kt + 1 < nt) {
      if (kt + 2 < nt)
        asm volatile("s_waitcnt vmcnt(3)" ::: "memory");  // t+1 landed
      else
        asm volatile("s_waitcnt vmcnt(0)" ::: "memory");
      __builtin_amdgcn_s_barrier();
    }
  }
#undef G3_STAGE

  const float sc = (QSC && n0 < 1024) ? 0.18033688011112042f : 1.0f;  // 0.125*log2e
#pragma unroll
  for (int m = 0; m < 4; ++m) {
    const int row_base = m0 + wm + m * 16 + lhi * 4;
#pragma unroll
    for (int n = 0; n < 4; ++n) {
      const int col = n0 + wn + n * 16 + l15;
      const float bv = bias[col];
#pragma unroll
      for (int r = 0; r < 4; ++r) {
        float v = (acc[m][n][r] + bv) * sc;
        if (RELU) v = v > 0.f ? v : 0.f;
        Cout[(size_t)(row_base + r) * N + col] = (bf16)v;
      }
    }
  }
}

// ---------------- GEMM: C[M,N] = act(A[M,K] @ Bw[N,K]^T + bias) (+res) ------
// TM x 128 tile, BK=32, 4 waves, counted-vmcnt depth-2, used for Wo/FFN2.
template <int TM, bool OUT_BF16, bool RELU, bool RES, bool QSC>
__global__ __launch_bounds__(256)
void gemm_bt(const bf16* __restrict__ A, const bf16* __restrict__ Bw,
             const float* __restrict__ bias, const float* __restrict__ res,
             void* __restrict__ Cout, int M, int N, int K) {
  constexpr int MR = TM / 32;
  constexpr int ACH = TM / 64;
  __shared__ bf16 As[3][TM * 32];
  __shared__ bf16 Bs[3][128 * 32];
  const int t = threadIdx.x, wave = t >> 6, lane = t & 63;
  const int l15 = lane & 15, lhi = lane >> 4;
  const int nwg = gridDim.x * gridDim.y;
  const int orig = blockIdx.y * gridDim.x + blockIdx.x;
  const int wgid = (orig & 7) * (nwg >> 3) + (orig >> 3);
  const int bx = wgid % gridDim.x, by = wgid / gridDim.x;
  const int m0 = by * TM, n0 = bx * 128;
  const int wm = (wave >> 1) * (TM / 2), wn = (wave & 1) * 64;
  const f32x4 z4 = {0.f, 0.f, 0.f, 0.f};
  f32x4 acc[MR][4];
#pragma unroll
  for (int m = 0; m < MR; ++m)
#pragma unroll
    for (int n = 0; n < 4; ++n) acc[m][n] = z4;

  int soff[2], srow[2], scol[2];
#pragma unroll
  for (int i = 0; i < 2; ++i) {
    soff[i] = (i * 4 + wave) * 1024 + lane * 16;
    srow[i] = soff[i] >> 6;
    scol[i] = (soff[i] & 63) >> 1;
  }

#define GEMM_STAGE(k0, bb)                                                    \
  do {                                                                        \
    _Pragma("unroll")                                                         \
    for (int i = 0; i < ACH; ++i)                                             \
      gload_lds16(A + (size_t)(m0 + srow[i]) * K + (k0) + scol[i],            \
                  (char*)As[bb] + soff[i]);                                   \
    _Pragma("unroll")                                                         \
    for (int i = 0; i < 2; ++i)                                               \
      gload_lds16(Bw + (size_t)(n0 + srow[i]) * K + (k0) + scol[i],           \
                  (char*)Bs[bb] + soff[i]);                                   \
  } while (0)

  const int nt = K >> 5;
  GEMM_STAGE(0, 0);
  GEMM_STAGE(32, 1);
  if constexpr (TM == 128)
    asm volatile("s_waitcnt vmcnt(4)" ::: "memory");
  else
    asm volatile("s_waitcnt vmcnt(3)" ::: "memory");
  __builtin_amdgcn_s_barrier();

  for (int kt = 0; kt < nt; ++kt) {
    if (kt + 2 < nt) GEMM_STAGE((kt + 2) * 32, (kt + 2) % 3);
    const bf16* Ac = As[kt % 3];
    const bf16* Bc = Bs[kt % 3];
    bf16x8 af[MR], bfr[4];
#pragma unroll
    for (int m = 0; m < MR; ++m)
      af[m] = *reinterpret_cast<const bf16x8*>(&Ac[(wm + m * 16 + l15) * 32 + lhi * 8]);
#pragma unroll
    for (int n = 0; n < 4; ++n)
      bfr[n] = *reinterpret_cast<const bf16x8*>(&Bc[(wn + n * 16 + l15) * 32 + lhi * 8]);
    __builtin_amdgcn_s_setprio(1);
#pragma unroll
    for (int m = 0; m < MR; ++m)
#pragma unroll
      for (int n = 0; n < 4; ++n) acc[m][n] = mfma16(af[m], bfr[n], acc[m][n]);
    __builtin_amdgcn_s_setprio(0);
    if (kt + 1 < nt) {
      if (kt + 2 < nt) {
        if constexpr (TM == 128)
          asm volatile("s_waitcnt vmcnt(4)" ::: "memory");
        else
          asm volatile("s_waitcnt vmcnt(3)" ::: "memory");
      } else {
        asm volatile("s_waitcnt vmcnt(0)" ::: "memory");
      }
      __builtin_amdgcn_s_barrier();
    }
  }
#undef GEMM_STAGE

  const float sc = (QSC && n0 < 1024) ? 0.18033688011112042f : 1.0f;
#pragma unroll
  for (int m = 0; m < MR; ++m) {
    const int row_base = m0 + wm + m * 16 + lhi * 4;
#pragma unroll
    for (int n = 0; n < 4; ++n) {
      const int col = n0 + wn + n * 16 + l15;
      const float bv = bias[col];
#pragma unroll
      for (int r = 0; r < 4; ++r) {
        const int row = row_base + r;
        float v = (acc[m][n][r] + bv) * sc;
        if (RELU) v = v > 0.f ? v : 0.f;
        if (RES) v += res[(size_t)row * N + col];
        if (OUT_BF16)
          ((bf16*)Cout)[(size_t)row * N + col] = (bf16)v;
        else
          ((float*)Cout)[(size_t)row * N + col] = v;
      }
    }
  }
}

// ---------------- Fused attention: QBLK=128, 8 waves, T14 ----------------
__global__ __launch_bounds__(512)
void attn_fused2(const bf16* __restrict__ Qp, const bf16* __restrict__ Kp,
                 const bf16* __restrict__ VTp, const int* __restrict__ mask,
                 float* __restrict__ probs, bf16* __restrict__ Ob) {
  constexpr int S = 2048, LD = 3072, KB = 128, NT = S / KB;
  __shared__ bf16 Kt[KB * 64];
  __shared__ bf16 Vt[64 * KB];
  __shared__ bf16 P[128 * KB];
  __shared__ float msk2[2][KB];
  const int t = threadIdx.x, wave = t >> 6, lane = t & 63;
  const int l15 = lane & 15, lhi = lane >> 4;
  const int flat = blockIdx.x + 16 * (blockIdx.y + 16 * blockIdx.z);
  const int wg = (flat & 7) * 64 + (flat >> 3);
  const int q0 = (wg & 15) * 128, h = (wg >> 4) & 15, b = wg >> 8;
  const int* mrow = mask + b * S;
  const f32x4 z4 = {0.f, 0.f, 0.f, 0.f};

  const bf16* kgp[2];
  const bf16* vgp[2];
  int soff[2];
#pragma unroll
  for (int i = 0; i < 2; ++i) {
    const int off = (i * 8 + wave) * 1024 + lane * 16;
    soff[i] = off;
    const int krow = off >> 7, kbin = off & 127;
    kgp[i] = Kp + (size_t)(b * S + krow) * LD + h * 64 + ((kbin ^ ((krow & 7) << 4)) >> 1);
    const int d = off >> 8, vbin = off & 255;
    vgp[i] = VTp + (size_t)((b * 16 + h) * 64 + d) * S + ((vbin ^ ((d & 7) << 4)) >> 1);
  }

  bf16x8 qf[2];
#pragma unroll
  for (int ks = 0; ks < 2; ++ks)
    qf[ks] = *reinterpret_cast<const bf16x8*>(
        Qp + (size_t)(b * S + q0 + wave * 16 + l15) * LD + h * 64 + ks * 32 + lhi * 8);

  // ================= pass A: l = sum over kv of exp2(s) =================
  bf16x8 kreg[2];
  float mnext;
#pragma unroll
  for (int i = 0; i < 2; ++i) kreg[i] = *reinterpret_cast<const bf16x8*>(kgp[i]);
  mnext = (t < KB) ? (mrow[t] ? 0.f : 1.f) : 0.f;
#pragma unroll
  for (int i = 0; i < 2; ++i)
    *reinterpret_cast<bf16x8*>((char*)Kt + soff[i]) = kreg[i];
  if (t < KB) msk2[0][t] = mnext;
  __syncthreads();

  float lpart = 0.f;
  for (int kt = 0; kt < NT; ++kt) {
    const int kv0 = kt * KB;
    if (kt + 1 < NT) {
#pragma unroll
      for (int i = 0; i < 2; ++i)
        kreg[i] = *reinterpret_cast<const bf16x8*>(kgp[i] + (size_t)(kv0 + KB) * LD);
      mnext = (t < KB) ? (mrow[kv0 + KB + t] ? 0.f : 1.f) : 0.f;
    }
    const char* kb = (kt & 1) ? (const char*)Vt : (const char*)Kt;
    const float* mc = msk2[kt & 1];
    f32x4 sa[8];
#pragma unroll
    for (int n = 0; n < 8; ++n) sa[n] = z4;
    __builtin_amdgcn_s_setprio(1);
#pragma unroll
    for (int ks = 0; ks < 2; ++ks)
#pragma unroll
      for (int n = 0; n < 8; ++n) {
        const int krow = n * 16 + l15;
        bf16x8 kf = *reinterpret_cast<const bf16x8*>(
            kb + krow * 128 + ((ks * 64 + lhi * 16) ^ ((krow & 7) << 4)));
        sa[n] = mfma16(kf, qf[ks], sa[n]);
      }
    __builtin_amdgcn_s_setprio(0);
#pragma unroll
    for (int n = 0; n < 8; ++n)
#pragma unroll
      for (int r = 0; r < 4; ++r)
        lpart += __builtin_exp2f(sa[n][r]) * mc[n * 16 + lhi * 4 + r];
    if (kt + 1 < NT) {
      char* kbn = ((kt + 1) & 1) ? (char*)Vt : (char*)Kt;
#pragma unroll
      for (int i = 0; i < 2; ++i)
        *reinterpret_cast<bf16x8*>(kbn + soff[i]) = kreg[i];
      if (t < KB) msk2[(kt + 1) & 1][t] = mnext;
    }
    __syncthreads();
  }
  lpart += __shfl_xor(lpart, 16);
  lpart += __shfl_xor(lpart, 32);
  const float il = 1.f / lpart;

  // ================= pass B: probs + PV =================
  f32x4 oa[4];
#pragma unroll
  for (int n = 0; n < 4; ++n) oa[n] = z4;
  float* pbase = probs + ((size_t)(b * 16 + h) * S + q0 + wave * 16 + l15) * S;
  const int prw = wave * 16 + l15;

  bf16x8 vreg[2];
#pragma unroll
  for (int i = 0; i < 2; ++i) {
    kreg[i] = *reinterpret_cast<const bf16x8*>(kgp[i]);
    vreg[i] = *reinterpret_cast<const bf16x8*>(vgp[i]);
  }
  mnext = (t < KB) ? (mrow[t] ? 0.f : 1.f) : 0.f;
#pragma unroll
  for (int i = 0; i < 2; ++i) {
    *reinterpret_cast<bf16x8*>((char*)Kt + soff[i]) = kreg[i];
    *reinterpret_cast<bf16x8*>((char*)Vt + soff[i]) = vreg[i];
  }
  if (t < KB) msk2[0][t] = mnext;
  __syncthreads();

  for (int kt = 0; kt < NT; ++kt) {
    const int kv0 = kt * KB;
    if (kt + 1 < NT) {
#pragma unroll
      for (int i = 0; i < 2; ++i) {
        kreg[i] = *reinterpret_cast<const bf16x8*>(kgp[i] + (size_t)(kv0 + KB) * LD);
        vreg[i] = *reinterpret_cast<const bf16x8*>(vgp[i] + kv0 + KB);
      }
      mnext = (t < KB) ? (mrow[kv0 + KB + t] ? 0.f : 1.f) : 0.f;
    }

    f32x4 sa[8];
#pragma unroll
    for (int n = 0; n < 8; ++n) sa[n] = z4;
    __builtin_amdgcn_s_setprio(1);
#pragma unroll
    for (int ks = 0; ks < 2; ++ks)
#pragma unroll
      for (int n = 0; n < 8; ++n) {
        const int krow = n * 16 + l15;
        bf16x8 kf = *reinterpret_cast<const bf16x8*>(
            (char*)Kt + krow * 128 + ((ks * 64 + lhi * 16) ^ ((krow & 7) << 4)));
        sa[n] = mfma16(kf, qf[ks], sa[n]);
      }
    __builtin_amdgcn_s_setprio(0);

#pragma unroll
    for (int n = 0; n < 8; ++n) {
      f32x4 praw, pn;
#pragma unroll
      for (int r = 0; r < 4; ++r) {
        praw[r] = __builtin_exp2f(sa[n][r]) * msk2[0][n * 16 + lhi * 4 + r];
        pn[r] = praw[r] * il;
      }
      __builtin_nontemporal_store(pn, reinterpret_cast<f32x4*>(pbase + kv0 + n * 16 + lhi * 4));
      bf16x4 pb;
      pb[0] = (bf16)praw[0]; pb[1] = (bf16)praw[1];
      pb[2] = (bf16)praw[2]; pb[3] = (bf16)praw[3];
      *reinterpret_cast<bf16x4*>(
          (char*)P + prw * 256 + ((n * 32 + lhi * 8) ^ ((prw & 7) << 4))) = pb;
    }
    __builtin_amdgcn_s_setprio(1);
#pragma unroll
    for (int ks = 0; ks < 4; ++ks) {
      bf16x8 pf = *reinterpret_cast<const bf16x8*>(
          (char*)P + prw * 256 + ((ks * 64 + lhi * 16) ^ ((prw & 7) << 4)));
#pragma unroll
      for (int nn = 0; nn < 4; ++nn) {
        const int vr = nn * 16 + l15;
        bf16x8 vf = *reinterpret_cast<const bf16x8*>(
            (char*)Vt + vr * 256 + ((ks * 64 + lhi * 16) ^ ((vr & 7) << 4)));
        oa[nn] = mfma16(pf, vf, oa[nn]);
      }
    }
    __builtin_amdgcn_s_setprio(0);
    __syncthreads();
    if (kt + 1 < NT) {
#pragma unroll
      for (int i = 0; i < 2; ++i) {
        *reinterpret_cast<bf16x8*>((char*)Kt + soff[i]) = kreg[i];
        *reinterpret_cast<bf16x8*>((char*)Vt + soff[i]) = vreg[i];
      }
      if (t < KB) msk2[0][t] = mnext;
    }
    __syncthreads();
  }

  float il4[4];
#pragma unroll
  for (int r = 0; r < 4; ++r) il4[r] = __shfl(il, lhi * 4 + r);
#pragma unroll
  for (int nn = 0; nn < 4; ++nn)
#pragma unroll
    for (int r = 0; r < 4; ++r)
      Ob[(size_t)(b * S + q0 + wave * 16 + lhi * 4 + r) * 1024 + h * 64 + nn * 16 + l15] =
          (bf16)(oa[nn][r] * il4[r]);
}

// ---------------- launch ----------------
extern "C" void kernel_launch(void* const* d_in, const int* in_sizes, int n_in,
                              void* d_out, int out_size, void* d_ws, size_t ws_size,
                              hipStream_t stream) {
  const float* src = (const float*)d_in[0];
  const int* mask = (const int*)d_in[1];
  const float* Wq = (const float*)d_in[2];
  const float* bq = (const float*)d_in[3];
  const float* Wk = (const float*)d_in[4];
  const float* bk = (const float*)d_in[5];
  const float* Wv = (const float*)d_in[6];
  const float* bv = (const float*)d_in[7];
  const float* Wo = (const float*)d_in[8];
  const float* bo = (const float*)d_in[9];
  const float* W1 = (const float*)d_in[10];
  const float* b1 = (const float*)d_in[11];
  const float* W2 = (const float*)d_in[12];
  const float* b2 = (const float*)d_in[13];
  const float* ln1g = (const float*)d_in[14];
  const float* ln1b = (const float*)d_in[15];
  const float* ln2g = (const float*)d_in[16];
  const float* ln2b = (const float*)d_in[17];

  float* out0 = (float*)d_out;                       // [2,2048,1024]
  float* probs = (float*)d_out + (size_t)4194304;    // [2,16,2048,2048]

  char* w = (char*)d_ws;
  const size_t MB = 1u << 20;
  bf16* wqkv = (bf16*)(w);              // [3072,1024] rows: Wq|Wk|Wv (6MB)
  bf16* wob = (bf16*)(w + 6 * MB);      // [1024,1024]
  bf16* w1b = (bf16*)(w + 8 * MB);      // [4096,1024]
  bf16* w2b = (bf16*)(w + 16 * MB);     // [1024,4096]
  bf16* xn = (bf16*)(w + 24 * MB);      // [4096,1024]
  bf16* QKV = (bf16*)(w + 32 * MB);     // [4096,3072] (24MB)
  bf16* Ob = (bf16*)(w + 56 * MB);      // [4096,1024]
  bf16* hb = (bf16*)(w + 32 * MB);      // [4096,4096] reuse (QKV dead by then)
  bf16* VT = (bf16*)(w + 64 * MB);      // [2,16,64,2048] (8MB); dead after attn
  float* s2 = (float*)(w + 64 * MB);    // [4096,1024] fp32 (16MB) overlays VT
  float* bqkv = (float*)(w + 80 * MB);  // [3072]

  // fused weight conversion + bias concat (1 launch)
  cvt_all<<<12291, 256, 0, stream>>>(Wq, Wk, Wv, Wo, W1, W2, bq, bk, bv,
                                     wqkv, wob, w1b, w2b, bqkv);

  // LN1
  ln_bf16<<<4096, 256, 0, stream>>>(src, ln1g, ln1b, xn);
  // fused QKV projection (Q part pre-scaled by 0.125*log2e): v3, 384 blocks
  gemm_bt3<false, true><<<dim3(12, 32), 512, 0, stream>>>(
      xn, wqkv, bqkv, QKV, 4096, 3072, 1024);
  // V transpose for attn staging
  tr_v<<<dim3(32, 16, 2), 256, 0, stream>>>(QKV, VT);
  // fused attention (QBLK=128, 8 waves)
  attn_fused2<<<dim3(16, 16, 2), 512, 0, stream>>>(
      QKV, QKV + 1024, VT, mask, probs, Ob);
  // Wo + residual(src) -> s2 (fp32): 64x128 tile, 512 blocks (2/CU)
  gemm_bt<64, false, false, true, false><<<dim3(8, 64), 256, 0, stream>>>(
      Ob, wob, bo, src, s2, 4096, 1024, 1024);
  // LN2
  ln_bf16<<<4096, 256, 0, stream>>>(s2, ln2g, ln2b, xn);
  // FFN1 + ReLU: v3, 512 blocks
  gemm_bt3<true, false><<<dim3(16, 32), 512, 0, stream>>>(
      xn, w1b, b1, hb, 4096, 4096, 1024);
  // FFN2 + residual(s2) -> out0: 64x128 tile, 512 blocks (2/CU)
  gemm_bt<64, false, false, true, false><<<dim3(8, 64), 256, 0, stream>>>(
      hb, w2b, b2, s2, out0, 4096, 1024, 4096);

  (void)in_sizes; (void)n_in; (void)out_size; (void)ws_size;
}